// Round 1
// baseline (533.391 us; speedup 1.0000x reference)
//
#include <hip/hip_runtime.h>
#include <hip/hip_bf16.h>
#include <stdint.h>

#define NNODES 50000
#define NEDGES 800000
#define DIN 128
#define DHID 200
#define MID1 256
#define MID2 400
#define SCAN_NB ((NNODES + 255) / 256)  // 196
#define NRB ((NNODES + 63) / 64)        // 782
#define RSPLIT 12
#define LOG2E 1.4426950408889634f
#define LN2 0.6931471805599453f

typedef __hip_bfloat16 bf16;
typedef __attribute__((ext_vector_type(8))) short short8;
typedef __attribute__((ext_vector_type(4))) float floatx4;
typedef unsigned short ushort;

__device__ __forceinline__ float b2f(bf16 v) { return __bfloat162float(v); }
__device__ __forceinline__ bf16 f2b(float v) { return __float2bfloat16(v); }
__device__ __forceinline__ float bits2f(ushort b) {
    unsigned u = ((unsigned)b) << 16;
    return __uint_as_float(u);
}
__device__ __forceinline__ ushort f2bits(float f) {
    bf16 h = __float2bfloat16(f);
    return *(ushort*)&h;
}
__device__ __forceinline__ float ldin(const void* p, size_t i, int f32) {
    return f32 ? ((const float*)p)[i] : __bfloat162float(((const bf16*)p)[i]);
}
__device__ __forceinline__ void ldin4(const void* p, size_t i, int f32, float* v) {
    if (f32) {
        float4 f = *(const float4*)((const float*)p + i);
        v[0] = f.x; v[1] = f.y; v[2] = f.z; v[3] = f.w;
    } else {
        ushort4 u = *(const ushort4*)((const bf16*)p + i);
        v[0] = bits2f(u.x); v[1] = bits2f(u.y); v[2] = bits2f(u.z); v[3] = bits2f(u.w);
    }
}
__device__ __forceinline__ float fexp2(float x) {
#if __has_builtin(__builtin_amdgcn_exp2f)
    return __builtin_amdgcn_exp2f(x);
#else
    return exp2f(x);
#endif
}
// LDS-only barrier: drains ds writes but leaves global prefetch loads in flight.
__device__ __forceinline__ void lds_barrier() {
    asm volatile("s_waitcnt lgkmcnt(0)\n\ts_barrier" ::: "memory");
}
__device__ __forceinline__ floatx4 mfma16(short8 a, short8 b, floatx4 c) {
    return __builtin_amdgcn_mfma_f32_16x16x32_bf16(a, b, c, 0, 0, 0);
}
// exp2-domain softmax accumulate over 4 packed channels
__device__ __forceinline__ void acc4(ushort4 u, float* s, float* p) {
    ushort uu[4];
    *(ushort4*)uu = u;
#pragma unroll
    for (int c = 0; c < 4; c++) {
        float v = bits2f(uu[c]);
        float ee = fexp2(v);
        s[c] += ee;
        p[c] = fmaf(v, ee, p[c]);
    }
}

// ---------------- CSR build (flag detection folded into hist) ----------------
__global__ void hist_kernel(const int* __restrict__ dst, int* __restrict__ counts,
                            const void* __restrict__ g, int* __restrict__ flag) {
    int e = blockIdx.x * blockDim.x + threadIdx.x;
    if (e == 0)  // dtype flag: f32 word 0x3F800000, bf16 pair 0x3F803F80
        *flag = (((const unsigned*)g)[0] == 0x3F800000u) ? 1 : 0;
    if (e < NEDGES) atomicAdd(&counts[dst[e]], 1);
}

__global__ __launch_bounds__(256) void scanA_kernel(const int* __restrict__ counts,
                                                    int* __restrict__ rowptr,
                                                    int* __restrict__ blocksums) {
    __shared__ int sh[256];
    int t = threadIdx.x, b = blockIdx.x;
    int i = b * 256 + t;
    int v = (i < NNODES) ? counts[i] : 0;
    sh[t] = v;
    __syncthreads();
#pragma unroll
    for (int off = 1; off < 256; off <<= 1) {
        int o = (t >= off) ? sh[t - off] : 0;
        __syncthreads();
        sh[t] += o;
        __syncthreads();
    }
    if (i < NNODES) rowptr[i] = sh[t] - v;  // local exclusive
    if (t == 255) blocksums[b] = sh[255];
}

// merged B+C: every block re-scans the 196 block sums locally, applies its offset.
__global__ __launch_bounds__(256) void scanC_kernel(int* __restrict__ rowptr,
                                                    int* __restrict__ cursor,
                                                    const int* __restrict__ blocksums) {
    __shared__ int sh[256];
    int t = threadIdx.x, b = blockIdx.x;
    sh[t] = (t < SCAN_NB) ? blocksums[t] : 0;
    __syncthreads();
#pragma unroll
    for (int off = 1; off < 256; off <<= 1) {
        int o = (t >= off) ? sh[t - off] : 0;
        __syncthreads();
        sh[t] += o;
        __syncthreads();
    }
    int boff = (b > 0) ? sh[b - 1] : 0;  // exclusive prefix of this block
    int i = b * 256 + t;
    if (i < NNODES) {
        int r = rowptr[i] + boff;
        rowptr[i] = r;
        cursor[i] = r;
    }
    if (i == 0) rowptr[NNODES] = NEDGES;
}

__global__ void scatter_kernel(const int* __restrict__ src, const int* __restrict__ dst,
                               int* __restrict__ cursor, int* __restrict__ ssrc) {
    int e = blockIdx.x * blockDim.x + threadIdx.x;
    if (e < NEDGES) {
        int p = atomicAdd(&cursor[dst[e]], 1);
        ssrc[p] = src[e];
    }
}

// ---------------- prep: 3 weight transposes + M1 exp2-domain msg table ----------------
#define TW (DIN * MID1 + MID1 * DHID + DHID * MID2)  // 163968
__global__ __launch_bounds__(256) void prep_kernel(const void* __restrict__ W1, bf16* __restrict__ Wt1,
                                                   const void* __restrict__ W2, bf16* __restrict__ Wt2,
                                                   const void* __restrict__ W3, bf16* __restrict__ Wt3,
                                                   const void* __restrict__ X, bf16* __restrict__ M1,
                                                   ushort* __restrict__ dummy,
                                                   const int* __restrict__ flag) {
    const int S1 = DIN * MID1, S2 = MID1 * DHID;
    int f32 = *flag;
    int idx = blockIdx.x * 256 + threadIdx.x;
    if (idx < TW) {
        const void* W;
        bf16* Wt;
        int K, N, li;
        if (idx < S1) { W = W1; Wt = Wt1; K = DIN; N = MID1; li = idx; }
        else if (idx < S1 + S2) { W = W2; Wt = Wt2; K = MID1; N = DHID; li = idx - S1; }
        else { W = W3; Wt = Wt3; K = DHID; N = MID2; li = idx - S1 - S2; }
        int k = li / N, n = li - k * N;
        Wt[(size_t)n * K + k] = f2b(ldin(W, li, f32));
    }
    if (idx < DHID) dummy[idx] = 0xC300;  // bf16(-128): exp2 -> 0, a softmax no-op row
    int i = idx * 4;
    if (i < NNODES * DIN) {
        float v[4];
        ldin4(X, i, f32, v);
        ushort4 o;
        o.x = f2bits((fmaxf(v[0], 0.f) + 1e-7f) * LOG2E);
        o.y = f2bits((fmaxf(v[1], 0.f) + 1e-7f) * LOG2E);
        o.z = f2bits((fmaxf(v[2], 0.f) + 1e-7f) * LOG2E);
        o.w = f2bits((fmaxf(v[3], 0.f) + 1e-7f) * LOG2E);
        *(ushort4*)(M1 + i) = o;
    }
}

// ---------------- aggregation: exp2 domain, MLP=8, 32-bit byte-offset shfl ----------
// DIN=128: 2 nodes per wave (half-wave = 32 lanes x 4 ch)
__global__ __launch_bounds__(256) void agg1_kernel(const void* __restrict__ X,
                                                   const bf16* __restrict__ M1,
                                                   const int* __restrict__ rowptr,
                                                   const int* __restrict__ ssrc,
                                                   const int* __restrict__ flag,
                                                   bf16* __restrict__ out) {
    int f32 = *flag;
    int hl = threadIdx.x & 31;
    int n = blockIdx.x * 8 + (threadIdx.x >> 5);
    int r0 = rowptr[n];
    int deg = rowptr[n + 1] - r0;
    const char* M1b = (const char*)M1;
    int boff = hl << 3;
    float s[4] = {0.f, 0.f, 0.f, 0.f}, p[4] = {0.f, 0.f, 0.f, 0.f};
    for (int base = 0; base < deg; base += 32) {
        int cnt = min(32, deg - base);
        int eo = ((base + hl < deg) ? ssrc[r0 + base + hl] : 0) << 8;
        int i = 0;
        for (; i + 7 < cnt; i += 8) {
            ushort4 u[8];
#pragma unroll
            for (int k = 0; k < 8; k++) {
                int o = __shfl(eo, i + k, 32) + boff;
                u[k] = *(const ushort4*)(M1b + o);
            }
#pragma unroll
            for (int k = 0; k < 8; k++) acc4(u[k], s, p);
        }
        for (; i < cnt; i++) {
            int o = __shfl(eo, i, 32) + boff;
            acc4(*(const ushort4*)(M1b + o), s, p);
        }
    }
    float xc[4];
    ldin4(X, (size_t)n * DIN + 4 * hl, f32, xc);
    ushort4 o;
    o.x = f2bits(fmaf(LN2, p[0] / (s[0] + 1e-16f), xc[0]));
    o.y = f2bits(fmaf(LN2, p[1] / (s[1] + 1e-16f), xc[1]));
    o.z = f2bits(fmaf(LN2, p[2] / (s[2] + 1e-16f), xc[2]));
    o.w = f2bits(fmaf(LN2, p[3] / (s[3] + 1e-16f), xc[3]));
    *(ushort4*)(out + (size_t)n * DIN + 4 * hl) = o;
}

// DHID=200: 1 node per wave (lanes 0..49 x 4 ch); M2 holds (h+eps)*log2e.
// NEW: edge-source indices are wave-uniform -> scalar s_load path (readfirstlane),
// saddr gathers with loop-invariant voffset; remainder handled by one masked
// 8-batch redirected to the dummy (-128) row instead of a serial scalar tail.
__global__ __launch_bounds__(256) void agg2_kernel(const bf16* __restrict__ M2,
                                                   const int* __restrict__ rowptr,
                                                   const int* __restrict__ ssrc,
                                                   const ushort* __restrict__ dummy,
                                                   bf16* __restrict__ out) {
    int lane = threadIdx.x & 63;
    int n = blockIdx.x * 4 + (threadIdx.x >> 6);
    int r0 = __builtin_amdgcn_readfirstlane(rowptr[n]);
    int deg = __builtin_amdgcn_readfirstlane(rowptr[n + 1]) - r0;
    bool act = lane < 50;
    int boff = (act ? lane : 49) << 3;  // byte offset within 400B row (clamped for idle lanes)
    const char* M2b = (const char*)M2;
    const char* dp = (const char*)dummy;
    float s[4] = {0.f, 0.f, 0.f, 0.f}, p[4] = {0.f, 0.f, 0.f, 0.f};
    int nfull = deg >> 3;
    for (int b = 0; b < nfull; b++) {
        const int* ep = ssrc + r0 + (b << 3);  // uniform -> s_load
        ushort4 u[8];
#pragma unroll
        for (int k = 0; k < 8; k++)
            u[k] = *(const ushort4*)(M2b + (size_t)((unsigned)ep[k] * 400u) + boff);
#pragma unroll
        for (int k = 0; k < 8; k++) acc4(u[k], s, p);
    }
    int rem = deg & 7;
    if (rem) {
        const int* ep = ssrc + r0 + (nfull << 3);
        ushort4 u[8];
#pragma unroll
        for (int k = 0; k < 8; k++) {
            const char* rp = (k < rem) ? (M2b + (size_t)((unsigned)ep[k] * 400u)) : dp;
            u[k] = *(const ushort4*)(rp + boff);
        }
#pragma unroll
        for (int k = 0; k < 8; k++) acc4(u[k], s, p);
    }
    if (act) {
        ushort4 u = *(const ushort4*)(M2b + (size_t)n * 400 + boff);
        float vn[4] = {bits2f(u.x), bits2f(u.y), bits2f(u.z), bits2f(u.w)};
        ushort4 o;
        o.x = f2bits(LN2 * (p[0] / (s[0] + 1e-16f) + vn[0]) - 1e-7f);
        o.y = f2bits(LN2 * (p[1] / (s[1] + 1e-16f) + vn[1]) - 1e-7f);
        o.z = f2bits(LN2 * (p[2] / (s[2] + 1e-16f) + vn[2]) - 1e-7f);
        o.w = f2bits(LN2 * (p[3] / (s[3] + 1e-16f) + vn[3]) - 1e-7f);
        *(ushort4*)(out + (size_t)n * DHID + 4 * lane) = o;
    }
}

// ---------------- pipelined stripe MFMA GEMM (col-splittable) ----------------
// cbase: column offset for bias lookup only (memory addressing stays local).
template <int MODE, int NT>
__global__ __launch_bounds__(256) void stripe_gemm(const bf16* __restrict__ A,
                                                   const bf16* __restrict__ Bt,
                                                   const void* __restrict__ bias,
                                                   const int* __restrict__ flag,
                                                   const float* __restrict__ sc,
                                                   const float* __restrict__ offs,
                                                   bf16* __restrict__ Out,
                                                   float* __restrict__ psum,
                                                   float* __restrict__ psq,
                                                   int cbase,
                                                   int M, int K, int NC, int pstride) {
    constexpr int NTW = (NT + 3) / 4;
    __shared__ short As[64][40];
    __shared__ short Bs[NT * 16][40];
    int f32 = *flag;
    int tid = threadIdx.x;
    int row0 = blockIdx.x * 64;
    int cb = blockIdx.y * NC;
    int L = tid & 63, w = tid >> 6;
    int lm = L & 15, q = L >> 4;
    int sm = tid >> 2, sk = (tid & 3) * 8;
    floatx4 acc[4][NTW];
#pragma unroll
    for (int i = 0; i < 4; i++)
#pragma unroll
        for (int j = 0; j < NTW; j++) acc[i][j] = (floatx4){0.f, 0.f, 0.f, 0.f};
    int KP = (K + 31) & ~31;

    uint4 pa = {0, 0, 0, 0};
    uint4 pb[NTW];
    float psc[8], pof[8];
    auto prefetch = [&](int k0) {
        int gm = row0 + sm, gk = k0 + sk;
        pa = (uint4){0, 0, 0, 0};
        if (gm < M && gk < K) {
            pa = *(const uint4*)(A + (size_t)gm * K + gk);
            if (MODE == 1) {
                *(float4*)&psc[0] = *(const float4*)(sc + gk);
                *(float4*)&psc[4] = *(const float4*)(sc + gk + 4);
                *(float4*)&pof[0] = *(const float4*)(offs + gk);
                *(float4*)&pof[4] = *(const float4*)(offs + gk + 4);
            }
        }
#pragma unroll
        for (int j = 0; j < NTW; j++) {
            int idx = tid + j * 256;
            int n = idx >> 2, kk = (idx & 3) * 8;
            int gk2 = k0 + kk;
            pb[j] = (uint4){0, 0, 0, 0};
            if (idx < NT * 64 && n < NC && gk2 < K)
                pb[j] = *(const uint4*)(Bt + (size_t)(cb + n) * K + gk2);
        }
    };
    prefetch(0);

    for (int k0 = 0; k0 < KP; k0 += 32) {
        {
            uint4 val = pa;
            if (MODE == 1) {
                int gm = row0 + sm, gk = k0 + sk;
                if (gm < M && gk < K) {
                    ushort us[8];
                    *(uint4*)us = val;
#pragma unroll
                    for (int j8 = 0; j8 < 8; j8++)
                        us[j8] = f2bits(fmaxf(bits2f(us[j8]) * psc[j8] + pof[j8], 0.f));
                    val = *(uint4*)us;
                }
            }
            *(uint4*)&As[sm][sk] = val;
        }
#pragma unroll
        for (int j = 0; j < NTW; j++) {
            int idx = tid + j * 256;
            if (idx < NT * 64) {
                int n = idx >> 2, kk = (idx & 3) * 8;
                *(uint4*)&Bs[n][kk] = pb[j];
            }
        }
        if (k0 + 32 < KP) prefetch(k0 + 32);
        lds_barrier();
        short8 a[4];
#pragma unroll
        for (int i = 0; i < 4; i++) a[i] = *(const short8*)&As[i * 16 + lm][q * 8];
#pragma unroll
        for (int j = 0; j < NTW; j++) {
            int tt = w * NTW + j;
            if (tt < NT) {
                short8 b = *(const short8*)&Bs[tt * 16 + lm][q * 8];
#pragma unroll
                for (int i = 0; i < 4; i++) acc[i][j] = mfma16(a[i], b, acc[i][j]);
            }
        }
        __syncthreads();
    }

#pragma unroll
    for (int j = 0; j < NTW; j++) {
        int tt = w * NTW + j;
        if (tt >= NT) continue;
        int gn = tt * 16 + lm;
        bool gok = gn < NC;
        float bb = gok ? ldin(bias, cbase + cb + gn, f32) : 0.f;
        float csum = 0.f, csq = 0.f;
#pragma unroll
        for (int i = 0; i < 4; i++) {
#pragma unroll
            for (int r = 0; r < 4; r++) {
                int gm = row0 + i * 16 + q * 4 + r;
                if (gm < M && gok) {
                    float v = acc[i][j][r] + bb;
                    if (MODE == 0) Out[(size_t)gm * pstride + cb + gn] = f2b(v);
                    if (MODE == 1)
                        Out[(size_t)gm * pstride + cb + gn] = f2b((fmaxf(v, 0.f) + 1e-7f) * LOG2E);
                    if (MODE != 1) { csum += v; csq += v * v; }
                }
            }
        }
        if (MODE != 1) {
            csum += __shfl_xor(csum, 16, 64); csq += __shfl_xor(csq, 16, 64);
            csum += __shfl_xor(csum, 32, 64); csq += __shfl_xor(csq, 32, 64);
            if (q == 0 && gok) {
                psum[(size_t)blockIdx.x * pstride + cb + gn] = csum;
                psq[(size_t)blockIdx.x * pstride + cb + gn] = csq;
            }
        }
    }
}

// two-stage stats reduction (grid (NC/64, RSPLIT) -> real parallelism; 12-contender atomics)
__global__ __launch_bounds__(256) void stats_reduce(const float* __restrict__ psum,
                                                    const float* __restrict__ psq,
                                                    float* __restrict__ bnsum,
                                                    float* __restrict__ bnsumsq,
                                                    int NB, int NC) {
    __shared__ float shs[4][64], shq[4][64];
    int cc = threadIdx.x & 63;
    int c = blockIdx.x * 64 + cc;
    int ro = threadIdx.x >> 6;
    int chunk = (NB + RSPLIT - 1) / RSPLIT;
    int b0 = blockIdx.y * chunk;
    int b1 = min(b0 + chunk, NB);
    float s = 0.f, sq = 0.f;
    if (c < NC) {
        for (int b = b0 + ro; b < b1; b += 4) {
            s += psum[(size_t)b * NC + c];
            sq += psq[(size_t)b * NC + c];
        }
    }
    shs[ro][cc] = s;
    shq[ro][cc] = sq;
    __syncthreads();
    if (threadIdx.x < 64) {
        int gc = blockIdx.x * 64 + threadIdx.x;
        if (gc < NC) {
            int t = threadIdx.x;
            float ts = shs[0][t] + shs[1][t] + shs[2][t] + shs[3][t];
            float tq = shq[0][t] + shq[1][t] + shq[2][t] + shq[3][t];
            atomicAdd(&bnsum[gc], ts);
            atomicAdd(&bnsumsq[gc], tq);
        }
    }
}

// fold BN stats: h_norm = h*sc + off  (cbase offsets the gamma/beta lookup)
__global__ void bn_finish(const float* __restrict__ sum, const float* __restrict__ sumsq,
                          const void* __restrict__ g, const void* __restrict__ be,
                          const int* __restrict__ flag,
                          float* __restrict__ sc, float* __restrict__ off, int cbase, int C) {
    int f32 = *flag;
    int c = blockIdx.x * blockDim.x + threadIdx.x;
    if (c < C) {
        float mu = sum[c] / (float)NNODES;
        float var = fmaxf(sumsq[c] / (float)NNODES - mu * mu, 0.f);
        float rstd = rsqrtf(var + 1e-5f);
        float s = rstd * ldin(g, cbase + c, f32);
        sc[c] = s;
        off[c] = ldin(be, cbase + c, f32) - mu * s;
    }
}

// Streaming BN+ReLU + 2-column matvec over stored H2 half (replaces the MFMA recompute).
// HALF==0: write partial to fscr.  HALF==1: combine, +b2, relu, write final output.
template <int HALF>
__global__ __launch_bounds__(256) void bn_tail(const bf16* __restrict__ H2,
                                               const float* __restrict__ sc,
                                               const float* __restrict__ off,
                                               const void* __restrict__ w2,
                                               const void* __restrict__ b2,
                                               const int* __restrict__ flag,
                                               float* __restrict__ fscr,
                                               void* __restrict__ outp) {
    int f32 = *flag;
    int lane = threadIdx.x & 63;
    int n = blockIdx.x * 4 + (threadIdx.x >> 6);
    float o0 = 0.f, o1 = 0.f;
    if (lane < 50) {
        int c0 = lane * 4;
        ushort4 u = *(const ushort4*)(H2 + (size_t)n * DHID + c0);
        float4 scv = *(const float4*)(sc + c0);
        float4 ofv = *(const float4*)(off + c0);
        float hv[4] = {bits2f(u.x), bits2f(u.y), bits2f(u.z), bits2f(u.w)};
        float scvv[4] = {scv.x, scv.y, scv.z, scv.w};
        float ofvv[4] = {ofv.x, ofv.y, ofv.z, ofv.w};
#pragma unroll
        for (int c = 0; c < 4; c++) {
            float v = fmaxf(fmaf(hv[c], scvv[c], ofvv[c]), 0.f);
            int gc = HALF * DHID + c0 + c;
            o0 = fmaf(v, ldin(w2, 2 * gc, f32), o0);
            o1 = fmaf(v, ldin(w2, 2 * gc + 1, f32), o1);
        }
    }
#pragma unroll
    for (int d = 1; d < 64; d <<= 1) {
        o0 += __shfl_xor(o0, d, 64);
        o1 += __shfl_xor(o1, d, 64);
    }
    if (lane == 0) {
        if (HALF == 0) {
            fscr[(size_t)n * 2 + 0] = o0;
            fscr[(size_t)n * 2 + 1] = o1;
        } else {
            float v0 = fmaxf(fscr[(size_t)n * 2 + 0] + o0 + ldin(b2, 0, f32), 0.f);
            float v1 = fmaxf(fscr[(size_t)n * 2 + 1] + o1 + ldin(b2, 1, f32), 0.f);
            if (f32) {
                ((float*)outp)[2 * n] = v0;
                ((float*)outp)[2 * n + 1] = v1;
            } else {
                ((bf16*)outp)[2 * n] = f2b(v0);
                ((bf16*)outp)[2 * n + 1] = f2b(v1);
            }
        }
    }
}

extern "C" void kernel_launch(void* const* d_in, const int* in_sizes, int n_in,
                              void* d_out, int out_size, void* d_ws, size_t ws_size,
                              hipStream_t stream) {
    const void* x = d_in[0];
    const int* ei = (const int*)d_in[1];
    const void* c1_w1 = d_in[2];
    const void* c1_b1 = d_in[3];
    const void* c1_g = d_in[4];
    const void* c1_be = d_in[5];
    const void* c1_w2 = d_in[6];
    const void* c1_b2 = d_in[7];
    const void* c2_w1 = d_in[8];
    const void* c2_b1 = d_in[9];
    const void* c2_g = d_in[10];
    const void* c2_be = d_in[11];
    const void* c2_w2 = d_in[12];
    const void* c2_b2 = d_in[13];

    const int* src = ei;
    const int* dst = ei + NEDGES;

    // -------- workspace layout (liveness-overlaid, ~49.4 MB) --------
    uint8_t* w = (uint8_t*)d_ws;
    int* rowptr = (int*)(w + 0);
    int* counts = (int*)(w + 204800);
    int* cursor = (int*)(w + 409600);
    bf16* wT1 = (bf16*)(w + 204800);        // overlays counts (written post-scan)
    bf16* wT2 = (bf16*)(w + 270336);
    bf16* wT3 = (bf16*)(w + 409600);        // overlays cursor (written post-scatter)
    int* ssrc = (int*)(w + 614400);
    float* bnbuf = (float*)(w + 3814400);
    float* sum1 = bnbuf, *sumsq1 = bnbuf + 256;
    float* sum2 = bnbuf + 512, *sumsq2 = bnbuf + 912;
    float* sc1 = bnbuf + 1312, *off1 = bnbuf + 1568;
    float* sc2 = bnbuf + 1824, *off2 = bnbuf + 2224;
    int* flag_in = (int*)(bnbuf + 2624);
    int* blocksums = (int*)(bnbuf + 2640);   // 196 ints -> ends at float idx 2836
    ushort* dummyrow = (ushort*)(bnbuf + 2840);  // 200 ushorts (400B) dummy msg row
    uint8_t* bufA = w + 3830784;   // 20MB: out1[12.8MB] -> h1/M2[20MB] -> H2 halves[20MB]
    uint8_t* bufB = w + 23830784;  // 25.6MB: M1 -> t1[25.6MB] -> out2[20MB] + ps2/pq2/fscr
    bf16* out1 = (bf16*)bufA;
    bf16* h1 = (bf16*)bufA;
    bf16* H2 = (bf16*)bufA;        // layer-2 hidden (one 200-col half at a time)
    bf16* M1 = (bf16*)bufB;
    bf16* t1 = (bf16*)bufB;
    bf16* out2 = (bf16*)bufB;
    float* ps1 = (float*)(bufA + 12800000);
    float* pq1 = ps1 + (size_t)NRB * MID1;
    float* ps2 = (float*)(bufB + 20000000);
    float* pq2 = ps2 + (size_t)NRB * MID2;
    float* fscr = (float*)(bufB + 22502400);  // 50000*2 floats = 400KB, after pq2

    hipMemsetAsync(counts, 0, NNODES * sizeof(int), stream);
    hipMemsetAsync(bnbuf, 0, 1312 * sizeof(float), stream);  // atomics target

    // CSR build (flag folded into hist; scanB folded into scanC)
    hist_kernel<<<(NEDGES + 255) / 256, 256, 0, stream>>>(dst, counts, c1_g, flag_in);
    scanA_kernel<<<SCAN_NB, 256, 0, stream>>>(counts, rowptr, blocksums);
    scanC_kernel<<<SCAN_NB, 256, 0, stream>>>(rowptr, cursor, blocksums);
    scatter_kernel<<<(NEDGES + 255) / 256, 256, 0, stream>>>(src, dst, cursor, ssrc);

    // weight transposes + M1 msg table + dummy row (single dispatch)
    prep_kernel<<<(NNODES * DIN / 4 + 255) / 256, 256, 0, stream>>>(
        c1_w1, wT1, c1_w2, wT2, c2_w1, wT3, x, M1, dummyrow, flag_in);

    // ----- layer 1 -----
    agg1_kernel<<<NNODES / 8, 256, 0, stream>>>(x, M1, rowptr, ssrc, flag_in, out1);
    stripe_gemm<0, 16><<<dim3(NRB, 1), 256, 0, stream>>>(out1, wT1, c1_b1, flag_in,
                                                         nullptr, nullptr, t1, ps1, pq1,
                                                         0, NNODES, DIN, MID1, MID1);
    stats_reduce<<<dim3((MID1 + 63) / 64, RSPLIT), 256, 0, stream>>>(ps1, pq1, sum1, sumsq1,
                                                                     NRB, MID1);
    bn_finish<<<1, 256, 0, stream>>>(sum1, sumsq1, c1_g, c1_be, flag_in, sc1, off1, 0, MID1);
    stripe_gemm<1, 13><<<dim3(NRB, 1), 256, 0, stream>>>(t1, wT2, c1_b2, flag_in,
                                                         sc1, off1, h1, nullptr, nullptr,
                                                         0, NNODES, MID1, DHID, DHID);

    // ----- layer 2 -----
    agg2_kernel<<<NNODES / 4, 256, 0, stream>>>(h1, rowptr, ssrc, dummyrow, out2);

    // half A (cols 0..199): GEMM writes H2 + stats, then BN fold + streaming tail
    stripe_gemm<0, 13><<<dim3(NRB, 1), 256, 0, stream>>>(out2, wT3, c2_b1, flag_in,
                                                         nullptr, nullptr, H2, ps2, pq2,
                                                         0, NNODES, DHID, DHID, DHID);
    stats_reduce<<<dim3((DHID + 63) / 64, RSPLIT), 256, 0, stream>>>(ps2, pq2, sum2, sumsq2,
                                                                     NRB, DHID);
    bn_finish<<<1, 256, 0, stream>>>(sum2, sumsq2, c2_g, c2_be, flag_in, sc2, off2, 0, DHID);
    bn_tail<0><<<NNODES / 4, 256, 0, stream>>>(H2, sc2, off2, c2_w2, c2_b2, flag_in,
                                               fscr, d_out);

    // half B (cols 200..399): reuses H2 buffer after tail A consumed it
    stripe_gemm<0, 13><<<dim3(NRB, 1), 256, 0, stream>>>(out2, wT3 + (size_t)DHID * DHID,
                                                         c2_b1, flag_in,
                                                         nullptr, nullptr, H2, ps2, pq2,
                                                         DHID, NNODES, DHID, DHID, DHID);
    stats_reduce<<<dim3((DHID + 63) / 64, RSPLIT), 256, 0, stream>>>(ps2, pq2,
                                                                     sum2 + DHID, sumsq2 + DHID,
                                                                     NRB, DHID);
    bn_finish<<<1, 256, 0, stream>>>(sum2 + DHID, sumsq2 + DHID, c2_g, c2_be, flag_in,
                                     sc2 + DHID, off2 + DHID, DHID, DHID);
    bn_tail<1><<<NNODES / 4, 256, 0, stream>>>(H2, sc2 + DHID, off2 + DHID, c2_w2, c2_b2,
                                               flag_in, fscr, d_out);
}

// Round 2
// 444.317 us; speedup vs baseline: 1.2005x; 1.2005x over previous
//
#include <hip/hip_runtime.h>
#include <hip/hip_bf16.h>
#include <stdint.h>

#define NNODES 50000
#define NEDGES 800000
#define DIN 128
#define DHID 200
#define MID1 256
#define MID2 400
#define SCAN_NB ((NNODES + 255) / 256)  // 196
#define NRB ((NNODES + 63) / 64)        // 782
#define RSPLIT 12
#define LOG2E 1.4426950408889634f
#define LN2 0.6931471805599453f

typedef __hip_bfloat16 bf16;
typedef __attribute__((ext_vector_type(8))) short short8;
typedef __attribute__((ext_vector_type(4))) float floatx4;
typedef unsigned short ushort;

__device__ __forceinline__ float b2f(bf16 v) { return __bfloat162float(v); }
__device__ __forceinline__ bf16 f2b(float v) { return __float2bfloat16(v); }
__device__ __forceinline__ float bits2f(ushort b) {
    unsigned u = ((unsigned)b) << 16;
    return __uint_as_float(u);
}
__device__ __forceinline__ ushort f2bits(float f) {
    bf16 h = __float2bfloat16(f);
    return *(ushort*)&h;
}
__device__ __forceinline__ float ldin(const void* p, size_t i, int f32) {
    return f32 ? ((const float*)p)[i] : __bfloat162float(((const bf16*)p)[i]);
}
__device__ __forceinline__ void ldin4(const void* p, size_t i, int f32, float* v) {
    if (f32) {
        float4 f = *(const float4*)((const float*)p + i);
        v[0] = f.x; v[1] = f.y; v[2] = f.z; v[3] = f.w;
    } else {
        ushort4 u = *(const ushort4*)((const bf16*)p + i);
        v[0] = bits2f(u.x); v[1] = bits2f(u.y); v[2] = bits2f(u.z); v[3] = bits2f(u.w);
    }
}
__device__ __forceinline__ float fexp2(float x) {
#if __has_builtin(__builtin_amdgcn_exp2f)
    return __builtin_amdgcn_exp2f(x);
#else
    return exp2f(x);
#endif
}
// LDS-only barrier: drains ds ops but leaves global (vmcnt) loads in flight.
// Used BOTH mid-iteration (after ds_writes, before ds_reads) and at end of
// iteration: the only inter-wave hazard at the loop-end barrier is LDS reuse,
// so lgkmcnt(0) suffices and the prefetch loads issued this iteration stay
// outstanding across the barrier (drained by the register dependency at the
// next iteration's ds_write). __syncthreads() would emit vmcnt(0) and expose
// full load latency every k-step (this was the 55us/3.5%-MfmaUtil stall).
__device__ __forceinline__ void lds_barrier() {
    asm volatile("s_waitcnt lgkmcnt(0)\n\ts_barrier" ::: "memory");
}
__device__ __forceinline__ floatx4 mfma16(short8 a, short8 b, floatx4 c) {
    return __builtin_amdgcn_mfma_f32_16x16x32_bf16(a, b, c, 0, 0, 0);
}
// exp2-domain softmax accumulate over 4 packed channels
__device__ __forceinline__ void acc4(ushort4 u, float* s, float* p) {
    ushort uu[4];
    *(ushort4*)uu = u;
#pragma unroll
    for (int c = 0; c < 4; c++) {
        float v = bits2f(uu[c]);
        float ee = fexp2(v);
        s[c] += ee;
        p[c] = fmaf(v, ee, p[c]);
    }
}

// ---------------- CSR build (flag detection folded into hist) ----------------
__global__ void hist_kernel(const int* __restrict__ dst, int* __restrict__ counts,
                            const void* __restrict__ g, int* __restrict__ flag) {
    int e = blockIdx.x * blockDim.x + threadIdx.x;
    if (e == 0)  // dtype flag: f32 word 0x3F800000, bf16 pair 0x3F803F80
        *flag = (((const unsigned*)g)[0] == 0x3F800000u) ? 1 : 0;
    if (e < NEDGES) atomicAdd(&counts[dst[e]], 1);
}

__global__ __launch_bounds__(256) void scanA_kernel(const int* __restrict__ counts,
                                                    int* __restrict__ rowptr,
                                                    int* __restrict__ blocksums) {
    __shared__ int sh[256];
    int t = threadIdx.x, b = blockIdx.x;
    int i = b * 256 + t;
    int v = (i < NNODES) ? counts[i] : 0;
    sh[t] = v;
    __syncthreads();
#pragma unroll
    for (int off = 1; off < 256; off <<= 1) {
        int o = (t >= off) ? sh[t - off] : 0;
        __syncthreads();
        sh[t] += o;
        __syncthreads();
    }
    if (i < NNODES) rowptr[i] = sh[t] - v;  // local exclusive
    if (t == 255) blocksums[b] = sh[255];
}

// merged B+C: every block re-scans the 196 block sums locally, applies its offset.
__global__ __launch_bounds__(256) void scanC_kernel(int* __restrict__ rowptr,
                                                    int* __restrict__ cursor,
                                                    const int* __restrict__ blocksums) {
    __shared__ int sh[256];
    int t = threadIdx.x, b = blockIdx.x;
    sh[t] = (t < SCAN_NB) ? blocksums[t] : 0;
    __syncthreads();
#pragma unroll
    for (int off = 1; off < 256; off <<= 1) {
        int o = (t >= off) ? sh[t - off] : 0;
        __syncthreads();
        sh[t] += o;
        __syncthreads();
    }
    int boff = (b > 0) ? sh[b - 1] : 0;  // exclusive prefix of this block
    int i = b * 256 + t;
    if (i < NNODES) {
        int r = rowptr[i] + boff;
        rowptr[i] = r;
        cursor[i] = r;
    }
    if (i == 0) rowptr[NNODES] = NEDGES;
}

__global__ void scatter_kernel(const int* __restrict__ src, const int* __restrict__ dst,
                               int* __restrict__ cursor, int* __restrict__ ssrc) {
    int e = blockIdx.x * blockDim.x + threadIdx.x;
    if (e < NEDGES) {
        int p = atomicAdd(&cursor[dst[e]], 1);
        ssrc[p] = src[e];
    }
}

// ---------------- prep: 3 weight transposes + M1 exp2-domain msg table ----------------
#define TW (DIN * MID1 + MID1 * DHID + DHID * MID2)  // 163968
__global__ __launch_bounds__(256) void prep_kernel(const void* __restrict__ W1, bf16* __restrict__ Wt1,
                                                   const void* __restrict__ W2, bf16* __restrict__ Wt2,
                                                   const void* __restrict__ W3, bf16* __restrict__ Wt3,
                                                   const void* __restrict__ X, bf16* __restrict__ M1,
                                                   ushort* __restrict__ dummy,
                                                   const int* __restrict__ flag) {
    const int S1 = DIN * MID1, S2 = MID1 * DHID;
    int f32 = *flag;
    int idx = blockIdx.x * 256 + threadIdx.x;
    if (idx < TW) {
        const void* W;
        bf16* Wt;
        int K, N, li;
        if (idx < S1) { W = W1; Wt = Wt1; K = DIN; N = MID1; li = idx; }
        else if (idx < S1 + S2) { W = W2; Wt = Wt2; K = MID1; N = DHID; li = idx - S1; }
        else { W = W3; Wt = Wt3; K = DHID; N = MID2; li = idx - S1 - S2; }
        int k = li / N, n = li - k * N;
        Wt[(size_t)n * K + k] = f2b(ldin(W, li, f32));
    }
    if (idx < DHID) dummy[idx] = 0xC300;  // bf16(-128): exp2 -> 0, a softmax no-op row
    int i = idx * 4;
    if (i < NNODES * DIN) {
        float v[4];
        ldin4(X, i, f32, v);
        ushort4 o;
        o.x = f2bits((fmaxf(v[0], 0.f) + 1e-7f) * LOG2E);
        o.y = f2bits((fmaxf(v[1], 0.f) + 1e-7f) * LOG2E);
        o.z = f2bits((fmaxf(v[2], 0.f) + 1e-7f) * LOG2E);
        o.w = f2bits((fmaxf(v[3], 0.f) + 1e-7f) * LOG2E);
        *(ushort4*)(M1 + i) = o;
    }
}

// ---------------- aggregation: exp2 domain, MLP=8, 32-bit byte-offset shfl ----------
// DIN=128: 2 nodes per wave (half-wave = 32 lanes x 4 ch)
__global__ __launch_bounds__(256) void agg1_kernel(const void* __restrict__ X,
                                                   const bf16* __restrict__ M1,
                                                   const int* __restrict__ rowptr,
                                                   const int* __restrict__ ssrc,
                                                   const int* __restrict__ flag,
                                                   bf16* __restrict__ out) {
    int f32 = *flag;
    int hl = threadIdx.x & 31;
    int n = blockIdx.x * 8 + (threadIdx.x >> 5);
    int r0 = rowptr[n];
    int deg = rowptr[n + 1] - r0;
    const char* M1b = (const char*)M1;
    int boff = hl << 3;
    float s[4] = {0.f, 0.f, 0.f, 0.f}, p[4] = {0.f, 0.f, 0.f, 0.f};
    for (int base = 0; base < deg; base += 32) {
        int cnt = min(32, deg - base);
        int eo = ((base + hl < deg) ? ssrc[r0 + base + hl] : 0) << 8;
        int i = 0;
        for (; i + 7 < cnt; i += 8) {
            ushort4 u[8];
#pragma unroll
            for (int k = 0; k < 8; k++) {
                int o = __shfl(eo, i + k, 32) + boff;
                u[k] = *(const ushort4*)(M1b + o);
            }
#pragma unroll
            for (int k = 0; k < 8; k++) acc4(u[k], s, p);
        }
        for (; i < cnt; i++) {
            int o = __shfl(eo, i, 32) + boff;
            acc4(*(const ushort4*)(M1b + o), s, p);
        }
    }
    float xc[4];
    ldin4(X, (size_t)n * DIN + 4 * hl, f32, xc);
    ushort4 o;
    o.x = f2bits(fmaf(LN2, p[0] / (s[0] + 1e-16f), xc[0]));
    o.y = f2bits(fmaf(LN2, p[1] / (s[1] + 1e-16f), xc[1]));
    o.z = f2bits(fmaf(LN2, p[2] / (s[2] + 1e-16f), xc[2]));
    o.w = f2bits(fmaf(LN2, p[3] / (s[3] + 1e-16f), xc[3]));
    *(ushort4*)(out + (size_t)n * DIN + 4 * hl) = o;
}

// DHID=200: 1 node per wave (lanes 0..49 x 4 ch); M2 holds (h+eps)*log2e.
// Edge-source indices are wave-uniform -> scalar s_load path (readfirstlane),
// saddr gathers with loop-invariant voffset; remainder handled by one masked
// 8-batch redirected to the dummy (-128) row instead of a serial scalar tail.
__global__ __launch_bounds__(256) void agg2_kernel(const bf16* __restrict__ M2,
                                                   const int* __restrict__ rowptr,
                                                   const int* __restrict__ ssrc,
                                                   const ushort* __restrict__ dummy,
                                                   bf16* __restrict__ out) {
    int lane = threadIdx.x & 63;
    int n = blockIdx.x * 4 + (threadIdx.x >> 6);
    int r0 = __builtin_amdgcn_readfirstlane(rowptr[n]);
    int deg = __builtin_amdgcn_readfirstlane(rowptr[n + 1]) - r0;
    bool act = lane < 50;
    int boff = (act ? lane : 49) << 3;  // byte offset within 400B row (clamped for idle lanes)
    const char* M2b = (const char*)M2;
    const char* dp = (const char*)dummy;
    float s[4] = {0.f, 0.f, 0.f, 0.f}, p[4] = {0.f, 0.f, 0.f, 0.f};
    int nfull = deg >> 3;
    for (int b = 0; b < nfull; b++) {
        const int* ep = ssrc + r0 + (b << 3);  // uniform -> s_load
        ushort4 u[8];
#pragma unroll
        for (int k = 0; k < 8; k++)
            u[k] = *(const ushort4*)(M2b + (size_t)((unsigned)ep[k] * 400u) + boff);
#pragma unroll
        for (int k = 0; k < 8; k++) acc4(u[k], s, p);
    }
    int rem = deg & 7;
    if (rem) {
        const int* ep = ssrc + r0 + (nfull << 3);
        ushort4 u[8];
#pragma unroll
        for (int k = 0; k < 8; k++) {
            const char* rp = (k < rem) ? (M2b + (size_t)((unsigned)ep[k] * 400u)) : dp;
            u[k] = *(const ushort4*)(rp + boff);
        }
#pragma unroll
        for (int k = 0; k < 8; k++) acc4(u[k], s, p);
    }
    if (act) {
        ushort4 u = *(const ushort4*)(M2b + (size_t)n * 400 + boff);
        float vn[4] = {bits2f(u.x), bits2f(u.y), bits2f(u.z), bits2f(u.w)};
        ushort4 o;
        o.x = f2bits(LN2 * (p[0] / (s[0] + 1e-16f) + vn[0]) - 1e-7f);
        o.y = f2bits(LN2 * (p[1] / (s[1] + 1e-16f) + vn[1]) - 1e-7f);
        o.z = f2bits(LN2 * (p[2] / (s[2] + 1e-16f) + vn[2]) - 1e-7f);
        o.w = f2bits(LN2 * (p[3] / (s[3] + 1e-16f) + vn[3]) - 1e-7f);
        *(ushort4*)(out + (size_t)n * DHID + 4 * lane) = o;
    }
}

// ---------------- pipelined stripe MFMA GEMM (col-splittable) ----------------
template <int MODE, int NT>
__global__ __launch_bounds__(256) void stripe_gemm(const bf16* __restrict__ A,
                                                   const bf16* __restrict__ Bt,
                                                   const void* __restrict__ bias,
                                                   const int* __restrict__ flag,
                                                   const float* __restrict__ sc,
                                                   const float* __restrict__ offs,
                                                   bf16* __restrict__ Out,
                                                   float* __restrict__ psum,
                                                   float* __restrict__ psq,
                                                   int M, int K, int NC, int pstride) {
    constexpr int NTW = (NT + 3) / 4;
    __shared__ short As[64][40];
    __shared__ short Bs[NT * 16][40];
    int f32 = *flag;
    int tid = threadIdx.x;
    int row0 = blockIdx.x * 64;
    int cb = blockIdx.y * NC;
    int L = tid & 63, w = tid >> 6;
    int lm = L & 15, q = L >> 4;
    int sm = tid >> 2, sk = (tid & 3) * 8;
    floatx4 acc[4][NTW];
#pragma unroll
    for (int i = 0; i < 4; i++)
#pragma unroll
        for (int j = 0; j < NTW; j++) acc[i][j] = (floatx4){0.f, 0.f, 0.f, 0.f};
    int KP = (K + 31) & ~31;

    uint4 pa = {0, 0, 0, 0};
    uint4 pb[NTW];
    float psc[8], pof[8];
    auto prefetch = [&](int k0) {
        int gm = row0 + sm, gk = k0 + sk;
        pa = (uint4){0, 0, 0, 0};
        if (gm < M && gk < K) {
            pa = *(const uint4*)(A + (size_t)gm * K + gk);
            if (MODE == 1) {
                *(float4*)&psc[0] = *(const float4*)(sc + gk);
                *(float4*)&psc[4] = *(const float4*)(sc + gk + 4);
                *(float4*)&pof[0] = *(const float4*)(offs + gk);
                *(float4*)&pof[4] = *(const float4*)(offs + gk + 4);
            }
        }
#pragma unroll
        for (int j = 0; j < NTW; j++) {
            int idx = tid + j * 256;
            int n = idx >> 2, kk = (idx & 3) * 8;
            int gk2 = k0 + kk;
            pb[j] = (uint4){0, 0, 0, 0};
            if (idx < NT * 64 && n < NC && gk2 < K)
                pb[j] = *(const uint4*)(Bt + (size_t)(cb + n) * K + gk2);
        }
    };
    prefetch(0);

    for (int k0 = 0; k0 < KP; k0 += 32) {
        {
            uint4 val = pa;
            if (MODE == 1) {
                int gm = row0 + sm, gk = k0 + sk;
                if (gm < M && gk < K) {
                    ushort us[8];
                    *(uint4*)us = val;
#pragma unroll
                    for (int j8 = 0; j8 < 8; j8++)
                        us[j8] = f2bits(fmaxf(bits2f(us[j8]) * psc[j8] + pof[j8], 0.f));
                    val = *(uint4*)us;
                }
            }
            *(uint4*)&As[sm][sk] = val;
        }
#pragma unroll
        for (int j = 0; j < NTW; j++) {
            int idx = tid + j * 256;
            if (idx < NT * 64) {
                int n = idx >> 2, kk = (idx & 3) * 8;
                *(uint4*)&Bs[n][kk] = pb[j];
            }
        }
        if (k0 + 32 < KP) prefetch(k0 + 32);
        lds_barrier();
        short8 a[4];
#pragma unroll
        for (int i = 0; i < 4; i++) a[i] = *(const short8*)&As[i * 16 + lm][q * 8];
#pragma unroll
        for (int j = 0; j < NTW; j++) {
            int tt = w * NTW + j;
            if (tt < NT) {
                short8 b = *(const short8*)&Bs[tt * 16 + lm][q * 8];
#pragma unroll
                for (int i = 0; i < 4; i++) acc[i][j] = mfma16(a[i], b, acc[i][j]);
            }
        }
        // lgkm-only barrier: next iter's ds_writes are safe once all waves'
        // ds_reads drained; prefetch loads stay in flight (no vmcnt drain).
        lds_barrier();
    }

#pragma unroll
    for (int j = 0; j < NTW; j++) {
        int tt = w * NTW + j;
        if (tt >= NT) continue;
        int gn = tt * 16 + lm;
        bool gok = gn < NC;
        float bb = gok ? ldin(bias, cb + gn, f32) : 0.f;
        float csum = 0.f, csq = 0.f;
#pragma unroll
        for (int i = 0; i < 4; i++) {
#pragma unroll
            for (int r = 0; r < 4; r++) {
                int gm = row0 + i * 16 + q * 4 + r;
                if (gm < M && gok) {
                    float v = acc[i][j][r] + bb;
                    if (MODE == 0) Out[(size_t)gm * pstride + cb + gn] = f2b(v);
                    if (MODE == 1)
                        Out[(size_t)gm * pstride + cb + gn] = f2b((fmaxf(v, 0.f) + 1e-7f) * LOG2E);
                    if (MODE != 1) { csum += v; csq += v * v; }
                }
            }
        }
        if (MODE != 1) {
            csum += __shfl_xor(csum, 16, 64); csq += __shfl_xor(csq, 16, 64);
            csum += __shfl_xor(csum, 32, 64); csq += __shfl_xor(csq, 32, 64);
            if (q == 0 && gok) {
                psum[(size_t)blockIdx.x * pstride + cb + gn] = csum;
                psq[(size_t)blockIdx.x * pstride + cb + gn] = csq;
            }
        }
    }
}

// two-stage stats reduction (grid (NC/64, RSPLIT) -> real parallelism; 12-contender atomics)
__global__ __launch_bounds__(256) void stats_reduce(const float* __restrict__ psum,
                                                    const float* __restrict__ psq,
                                                    float* __restrict__ bnsum,
                                                    float* __restrict__ bnsumsq,
                                                    int NB, int NC) {
    __shared__ float shs[4][64], shq[4][64];
    int cc = threadIdx.x & 63;
    int c = blockIdx.x * 64 + cc;
    int ro = threadIdx.x >> 6;
    int chunk = (NB + RSPLIT - 1) / RSPLIT;
    int b0 = blockIdx.y * chunk;
    int b1 = min(b0 + chunk, NB);
    float s = 0.f, sq = 0.f;
    if (c < NC) {
        for (int b = b0 + ro; b < b1; b += 4) {
            s += psum[(size_t)b * NC + c];
            sq += psq[(size_t)b * NC + c];
        }
    }
    shs[ro][cc] = s;
    shq[ro][cc] = sq;
    __syncthreads();
    if (threadIdx.x < 64) {
        int gc = blockIdx.x * 64 + threadIdx.x;
        if (gc < NC) {
            int t = threadIdx.x;
            float ts = shs[0][t] + shs[1][t] + shs[2][t] + shs[3][t];
            float tq = shq[0][t] + shq[1][t] + shq[2][t] + shq[3][t];
            atomicAdd(&bnsum[gc], ts);
            atomicAdd(&bnsumsq[gc], tq);
        }
    }
}

// fold BN stats: h_norm = h*sc + off
__global__ void bn_finish(const float* __restrict__ sum, const float* __restrict__ sumsq,
                          const void* __restrict__ g, const void* __restrict__ be,
                          const int* __restrict__ flag,
                          float* __restrict__ sc, float* __restrict__ off, int C) {
    int f32 = *flag;
    int c = blockIdx.x * blockDim.x + threadIdx.x;
    if (c < C) {
        float mu = sum[c] / (float)NNODES;
        float var = fmaxf(sumsq[c] / (float)NNODES - mu * mu, 0.f);
        float rstd = rsqrtf(var + 1e-5f);
        float s = rstd * ldin(g, c, f32);
        sc[c] = s;
        off[c] = ldin(be, c, f32) - mu * s;
    }
}

// Fused layer-2 tail, col-split (grid (NRB,2), 200 cols each)
__global__ __launch_bounds__(256) void fused_final_mfma(const bf16* __restrict__ out2,
                                                        const bf16* __restrict__ Wt3,
                                                        const void* __restrict__ b1,
                                                        const float* __restrict__ sc,
                                                        const float* __restrict__ off,
                                                        const void* __restrict__ w2,
                                                        const int* __restrict__ flag,
                                                        float* __restrict__ fscr, int M) {
    constexpr int NT = 13, NTW = 4, NCL = 200;
    __shared__ short As[64][40];
    __shared__ short Bs[NT * 16][40];
    __shared__ float red[64][2];
    int f32 = *flag;
    int tid = threadIdx.x;
    int L = tid & 63, w = tid >> 6;
    int lm = L & 15, q = L >> 4;
    int row0 = blockIdx.x * 64;
    int cb = blockIdx.y * NCL;
    int sm = tid >> 2, sk = (tid & 3) * 8;
    floatx4 acc[4][NTW];
#pragma unroll
    for (int i = 0; i < 4; i++)
#pragma unroll
        for (int j = 0; j < NTW; j++) acc[i][j] = (floatx4){0.f, 0.f, 0.f, 0.f};
    if (tid < 128) red[tid >> 1][tid & 1] = 0.f;

    uint4 pa = {0, 0, 0, 0};
    uint4 pb[NTW];
    auto prefetch = [&](int k0) {
        int gm = row0 + sm, gk = k0 + sk;
        pa = (uint4){0, 0, 0, 0};
        if (gm < M && gk < DHID) pa = *(const uint4*)(out2 + (size_t)gm * DHID + gk);
#pragma unroll
        for (int j = 0; j < NTW; j++) {
            int idx = tid + j * 256;
            int n = idx >> 2, kk = (idx & 3) * 8;
            int gk2 = k0 + kk;
            pb[j] = (uint4){0, 0, 0, 0};
            if (idx < NT * 64 && n < NCL && gk2 < DHID)
                pb[j] = *(const uint4*)(Wt3 + (size_t)(cb + n) * DHID + gk2);
        }
    };
    prefetch(0);

    for (int k0 = 0; k0 < 224; k0 += 32) {
        *(uint4*)&As[sm][sk] = pa;
#pragma unroll
        for (int j = 0; j < NTW; j++) {
            int idx = tid + j * 256;
            if (idx < NT * 64) {
                int n = idx >> 2, kk = (idx & 3) * 8;
                *(uint4*)&Bs[n][kk] = pb[j];
            }
        }
        if (k0 + 32 < 224) prefetch(k0 + 32);
        lds_barrier();
        short8 a[4];
#pragma unroll
        for (int i = 0; i < 4; i++) a[i] = *(const short8*)&As[i * 16 + lm][q * 8];
#pragma unroll
        for (int j = 0; j < NTW; j++) {
            int tt = w * NTW + j;
            if (tt < NT) {
                short8 b = *(const short8*)&Bs[tt * 16 + lm][q * 8];
#pragma unroll
                for (int i = 0; i < 4; i++) acc[i][j] = mfma16(a[i], b, acc[i][j]);
            }
        }
        // lgkm-only barrier (see stripe_gemm): keep prefetch loads in flight.
        lds_barrier();
    }

    float s0[4][4], s1[4][4];
#pragma unroll
    for (int i = 0; i < 4; i++)
#pragma unroll
        for (int r = 0; r < 4; r++) { s0[i][r] = 0.f; s1[i][r] = 0.f; }
#pragma unroll
    for (int j = 0; j < NTW; j++) {
        int tt = w * NTW + j;
        if (tt >= NT) continue;
        int gn = tt * 16 + lm;
        if (gn < NCL) {
            int gg = cb + gn;
            float bb = ldin(b1, gg, f32);
            float scv = sc[gg], ofv = off[gg];
            float w20 = ldin(w2, 2 * gg, f32), w21 = ldin(w2, 2 * gg + 1, f32);
#pragma unroll
            for (int i = 0; i < 4; i++)
#pragma unroll
                for (int r = 0; r < 4; r++) {
                    float vn = fmaxf((acc[i][j][r] + bb) * scv + ofv, 0.f);
                    s0[i][r] = fmaf(vn, w20, s0[i][r]);
                    s1[i][r] = fmaf(vn, w21, s1[i][r]);
                }
        }
    }
#pragma unroll
    for (int d = 1; d < 16; d <<= 1) {
#pragma unroll
        for (int i = 0; i < 4; i++)
#pragma unroll
            for (int r = 0; r < 4; r++) {
                s0[i][r] += __shfl_xor(s0[i][r], d, 64);
                s1[i][r] += __shfl_xor(s1[i][r], d, 64);
            }
    }
    if (lm == 0) {
#pragma unroll
        for (int i = 0; i < 4; i++)
#pragma unroll
            for (int r = 0; r < 4; r++) {
                atomicAdd(&red[i * 16 + q * 4 + r][0], s0[i][r]);
                atomicAdd(&red[i * 16 + q * 4 + r][1], s1[i][r]);
            }
    }
    __syncthreads();
    if (tid < 64) {
        int gm = row0 + tid;
        if (gm < M) {
            fscr[(size_t)gm * 4 + blockIdx.y * 2 + 0] = red[tid][0];
            fscr[(size_t)gm * 4 + blockIdx.y * 2 + 1] = red[tid][1];
        }
    }
}

// combine the two col-half partials: out = relu(p0+p1+b2)
__global__ void final_combine(const float* __restrict__ fscr, const void* __restrict__ b2,
                              const int* __restrict__ flag, void* __restrict__ outp, int M) {
    int f32 = *flag;
    int n = blockIdx.x * 256 + threadIdx.x;
    if (n < M) {
        float v0 = fmaxf(fscr[(size_t)n * 4 + 0] + fscr[(size_t)n * 4 + 2] + ldin(b2, 0, f32), 0.f);
        float v1 = fmaxf(fscr[(size_t)n * 4 + 1] + fscr[(size_t)n * 4 + 3] + ldin(b2, 1, f32), 0.f);
        if (f32) {
            ((float*)outp)[2 * n] = v0;
            ((float*)outp)[2 * n + 1] = v1;
        } else {
            ((bf16*)outp)[2 * n] = f2b(v0);
            ((bf16*)outp)[2 * n + 1] = f2b(v1);
        }
    }
}

extern "C" void kernel_launch(void* const* d_in, const int* in_sizes, int n_in,
                              void* d_out, int out_size, void* d_ws, size_t ws_size,
                              hipStream_t stream) {
    const void* x = d_in[0];
    const int* ei = (const int*)d_in[1];
    const void* c1_w1 = d_in[2];
    const void* c1_b1 = d_in[3];
    const void* c1_g = d_in[4];
    const void* c1_be = d_in[5];
    const void* c1_w2 = d_in[6];
    const void* c1_b2 = d_in[7];
    const void* c2_w1 = d_in[8];
    const void* c2_b1 = d_in[9];
    const void* c2_g = d_in[10];
    const void* c2_be = d_in[11];
    const void* c2_w2 = d_in[12];
    const void* c2_b2 = d_in[13];

    const int* src = ei;
    const int* dst = ei + NEDGES;

    // -------- workspace layout (liveness-overlaid, ~49.4 MB) --------
    uint8_t* w = (uint8_t*)d_ws;
    int* rowptr = (int*)(w + 0);
    int* counts = (int*)(w + 204800);
    int* cursor = (int*)(w + 409600);
    bf16* wT1 = (bf16*)(w + 204800);        // overlays counts (written post-scan)
    bf16* wT2 = (bf16*)(w + 270336);
    bf16* wT3 = (bf16*)(w + 409600);        // overlays cursor (written post-scatter)
    int* ssrc = (int*)(w + 614400);
    float* bnbuf = (float*)(w + 3814400);
    float* sum1 = bnbuf, *sumsq1 = bnbuf + 256;
    float* sum2 = bnbuf + 512, *sumsq2 = bnbuf + 912;
    float* sc1 = bnbuf + 1312, *off1 = bnbuf + 1568;
    float* sc2 = bnbuf + 1824, *off2 = bnbuf + 2224;
    int* flag_in = (int*)(bnbuf + 2624);
    int* blocksums = (int*)(bnbuf + 2640);       // 196 ints -> ends at float idx 2836
    ushort* dummyrow = (ushort*)(bnbuf + 2840);  // 200 ushorts (400B) dummy msg row
    uint8_t* bufA = w + 3830784;   // 20MB: out1[12.8MB] -> h1/M2'[20MB] -> fscr[0.8MB]
    uint8_t* bufB = w + 23830784;  // 25.6MB: M1 -> t1[25.6MB] -> out2[20MB]
    bf16* out1 = (bf16*)bufA;
    bf16* h1 = (bf16*)bufA;
    float* fscr = (float*)bufA;
    bf16* M1 = (bf16*)bufB;
    bf16* t1 = (bf16*)bufB;
    bf16* out2 = (bf16*)bufB;
    float* ps1 = (float*)(bufA + 12800000);
    float* pq1 = ps1 + (size_t)NRB * MID1;
    float* ps2 = (float*)(bufB + 20000000);
    float* pq2 = ps2 + (size_t)NRB * MID2;

    hipMemsetAsync(counts, 0, NNODES * sizeof(int), stream);
    hipMemsetAsync(bnbuf, 0, 1312 * sizeof(float), stream);  // atomics target

    // CSR build (flag folded into hist; scanB folded into scanC)
    hist_kernel<<<(NEDGES + 255) / 256, 256, 0, stream>>>(dst, counts, c1_g, flag_in);
    scanA_kernel<<<SCAN_NB, 256, 0, stream>>>(counts, rowptr, blocksums);
    scanC_kernel<<<SCAN_NB, 256, 0, stream>>>(rowptr, cursor, blocksums);
    scatter_kernel<<<(NEDGES + 255) / 256, 256, 0, stream>>>(src, dst, cursor, ssrc);

    // weight transposes + M1 msg table + dummy row (single dispatch)
    prep_kernel<<<(NNODES * DIN / 4 + 255) / 256, 256, 0, stream>>>(
        c1_w1, wT1, c1_w2, wT2, c2_w1, wT3, x, M1, dummyrow, flag_in);

    // ----- layer 1 -----
    agg1_kernel<<<NNODES / 8, 256, 0, stream>>>(x, M1, rowptr, ssrc, flag_in, out1);
    stripe_gemm<0, 16><<<dim3(NRB, 1), 256, 0, stream>>>(out1, wT1, c1_b1, flag_in,
                                                         nullptr, nullptr, t1, ps1, pq1,
                                                         NNODES, DIN, MID1, MID1);
    stats_reduce<<<dim3((MID1 + 63) / 64, RSPLIT), 256, 0, stream>>>(ps1, pq1, sum1, sumsq1,
                                                                     NRB, MID1);
    bn_finish<<<1, 256, 0, stream>>>(sum1, sumsq1, c1_g, c1_be, flag_in, sc1, off1, MID1);
    stripe_gemm<1, 13><<<dim3(NRB, 1), 256, 0, stream>>>(t1, wT2, c1_b2, flag_in,
                                                         sc1, off1, h1, nullptr, nullptr,
                                                         NNODES, MID1, DHID, DHID);

    // ----- layer 2 -----
    agg2_kernel<<<NNODES / 4, 256, 0, stream>>>(h1, rowptr, ssrc, dummyrow, out2);
    stripe_gemm<2, 13><<<dim3(NRB, 2), 256, 0, stream>>>(out2, wT3, c2_b1, flag_in,
                                                         nullptr, nullptr, nullptr, ps2, pq2,
                                                         NNODES, DHID, DHID, MID2);
    stats_reduce<<<dim3((MID2 + 63) / 64, RSPLIT), 256, 0, stream>>>(ps2, pq2, sum2, sumsq2,
                                                                     NRB, MID2);
    bn_finish<<<2, 256, 0, stream>>>(sum2, sumsq2, c2_g, c2_be, flag_in, sc2, off2, MID2);
    fused_final_mfma<<<dim3(NRB, 2), 256, 0, stream>>>(out2, wT3, c2_b1, sc2, off2,
                                                       c2_w2, flag_in, fscr, NNODES);
    final_combine<<<(NNODES + 255) / 256, 256, 0, stream>>>(fscr, c2_b2, flag_in,
                                                            d_out, NNODES);
}

// Round 3
// 442.409 us; speedup vs baseline: 1.2057x; 1.0043x over previous
//
#include <hip/hip_runtime.h>
#include <hip/hip_bf16.h>
#include <stdint.h>

#define NNODES 50000
#define NEDGES 800000
#define DIN 128
#define DHID 200
#define MID1 256
#define MID2 400
#define SCAN_NB ((NNODES + 255) / 256)  // 196
#define NRB ((NNODES + 63) / 64)        // 782
#define RSPLIT 12
#define LOG2E 1.4426950408889634f
#define LN2 0.6931471805599453f
// Gram (layer-2 BN stats): G = [out2 | 1]^T [out2 | 1], 208x208 padded
#define GK_SPLIT 96
#define GCH 208
#define GNP 40   // LDS node pad (32 nodes + 8) -> 80B row stride, 16B aligned

typedef __hip_bfloat16 bf16;
typedef __attribute__((ext_vector_type(8))) short short8;
typedef __attribute__((ext_vector_type(4))) float floatx4;
typedef unsigned short ushort;

__device__ __forceinline__ float b2f(bf16 v) { return __bfloat162float(v); }
__device__ __forceinline__ bf16 f2b(float v) { return __float2bfloat16(v); }
__device__ __forceinline__ float bits2f(ushort b) {
    unsigned u = ((unsigned)b) << 16;
    return __uint_as_float(u);
}
__device__ __forceinline__ ushort f2bits(float f) {
    bf16 h = __float2bfloat16(f);
    return *(ushort*)&h;
}
__device__ __forceinline__ float ldin(const void* p, size_t i, int f32) {
    return f32 ? ((const float*)p)[i] : __bfloat162float(((const bf16*)p)[i]);
}
__device__ __forceinline__ void ldin4(const void* p, size_t i, int f32, float* v) {
    if (f32) {
        float4 f = *(const float4*)((const float*)p + i);
        v[0] = f.x; v[1] = f.y; v[2] = f.z; v[3] = f.w;
    } else {
        ushort4 u = *(const ushort4*)((const bf16*)p + i);
        v[0] = bits2f(u.x); v[1] = bits2f(u.y); v[2] = bits2f(u.z); v[3] = bits2f(u.w);
    }
}
__device__ __forceinline__ float fexp2(float x) {
#if __has_builtin(__builtin_amdgcn_exp2f)
    return __builtin_amdgcn_exp2f(x);
#else
    return exp2f(x);
#endif
}
// LDS-only barrier: drains ds ops but leaves global (vmcnt) loads in flight.
__device__ __forceinline__ void lds_barrier() {
    asm volatile("s_waitcnt lgkmcnt(0)\n\ts_barrier" ::: "memory");
}
__device__ __forceinline__ floatx4 mfma16(short8 a, short8 b, floatx4 c) {
    return __builtin_amdgcn_mfma_f32_16x16x32_bf16(a, b, c, 0, 0, 0);
}
// exp2-domain softmax accumulate over 4 packed channels
__device__ __forceinline__ void acc4(ushort4 u, float* s, float* p) {
    ushort uu[4];
    *(ushort4*)uu = u;
#pragma unroll
    for (int c = 0; c < 4; c++) {
        float v = bits2f(uu[c]);
        float ee = fexp2(v);
        s[c] += ee;
        p[c] = fmaf(v, ee, p[c]);
    }
}

// ---------------- CSR build (flag detection folded into hist) ----------------
__global__ void hist_kernel(const int* __restrict__ dst, int* __restrict__ counts,
                            const void* __restrict__ g, int* __restrict__ flag) {
    int e = blockIdx.x * blockDim.x + threadIdx.x;
    if (e == 0)  // dtype flag: f32 word 0x3F800000, bf16 pair 0x3F803F80
        *flag = (((const unsigned*)g)[0] == 0x3F800000u) ? 1 : 0;
    if (e < NEDGES) atomicAdd(&counts[dst[e]], 1);
}

__global__ __launch_bounds__(256) void scanA_kernel(const int* __restrict__ counts,
                                                    int* __restrict__ rowptr,
                                                    int* __restrict__ blocksums) {
    __shared__ int sh[256];
    int t = threadIdx.x, b = blockIdx.x;
    int i = b * 256 + t;
    int v = (i < NNODES) ? counts[i] : 0;
    sh[t] = v;
    __syncthreads();
#pragma unroll
    for (int off = 1; off < 256; off <<= 1) {
        int o = (t >= off) ? sh[t - off] : 0;
        __syncthreads();
        sh[t] += o;
        __syncthreads();
    }
    if (i < NNODES) rowptr[i] = sh[t] - v;  // local exclusive
    if (t == 255) blocksums[b] = sh[255];
}

// merged B+C: every block re-scans the 196 block sums locally, applies its offset.
__global__ __launch_bounds__(256) void scanC_kernel(int* __restrict__ rowptr,
                                                    int* __restrict__ cursor,
                                                    const int* __restrict__ blocksums) {
    __shared__ int sh[256];
    int t = threadIdx.x, b = blockIdx.x;
    sh[t] = (t < SCAN_NB) ? blocksums[t] : 0;
    __syncthreads();
#pragma unroll
    for (int off = 1; off < 256; off <<= 1) {
        int o = (t >= off) ? sh[t - off] : 0;
        __syncthreads();
        sh[t] += o;
        __syncthreads();
    }
    int boff = (b > 0) ? sh[b - 1] : 0;  // exclusive prefix of this block
    int i = b * 256 + t;
    if (i < NNODES) {
        int r = rowptr[i] + boff;
        rowptr[i] = r;
        cursor[i] = r;
    }
    if (i == 0) rowptr[NNODES] = NEDGES;
}

__global__ void scatter_kernel(const int* __restrict__ src, const int* __restrict__ dst,
                               int* __restrict__ cursor, ushort* __restrict__ ssrc) {
    int e = blockIdx.x * blockDim.x + threadIdx.x;
    if (e < NEDGES) {
        int p = atomicAdd(&cursor[dst[e]], 1);
        ssrc[p] = (ushort)src[e];  // NNODES < 65536
    }
}

// ---------------- prep: 3 weight transposes + M1 exp2-domain msg table ----------------
#define TW (DIN * MID1 + MID1 * DHID + DHID * MID2)  // 163968
__global__ __launch_bounds__(256) void prep_kernel(const void* __restrict__ W1, bf16* __restrict__ Wt1,
                                                   const void* __restrict__ W2, bf16* __restrict__ Wt2,
                                                   const void* __restrict__ W3, bf16* __restrict__ Wt3,
                                                   const void* __restrict__ X, bf16* __restrict__ M1,
                                                   ushort* __restrict__ dummy,
                                                   const int* __restrict__ flag) {
    const int S1 = DIN * MID1, S2 = MID1 * DHID;
    int f32 = *flag;
    int idx = blockIdx.x * 256 + threadIdx.x;
    if (idx < TW) {
        const void* W;
        bf16* Wt;
        int K, N, li;
        if (idx < S1) { W = W1; Wt = Wt1; K = DIN; N = MID1; li = idx; }
        else if (idx < S1 + S2) { W = W2; Wt = Wt2; K = MID1; N = DHID; li = idx - S1; }
        else { W = W3; Wt = Wt3; K = DHID; N = MID2; li = idx - S1 - S2; }
        int k = li / N, n = li - k * N;
        Wt[(size_t)n * K + k] = f2b(ldin(W, li, f32));
    }
    if (idx < DHID) dummy[idx] = 0xC300;  // bf16(-128): exp2 -> 0, a softmax no-op row
    int i = idx * 4;
    if (i < NNODES * DIN) {
        float v[4];
        ldin4(X, i, f32, v);
        ushort4 o;
        o.x = f2bits((fmaxf(v[0], 0.f) + 1e-7f) * LOG2E);
        o.y = f2bits((fmaxf(v[1], 0.f) + 1e-7f) * LOG2E);
        o.z = f2bits((fmaxf(v[2], 0.f) + 1e-7f) * LOG2E);
        o.w = f2bits((fmaxf(v[3], 0.f) + 1e-7f) * LOG2E);
        *(ushort4*)(M1 + i) = o;
    }
}

// ---------------- aggregation: exp2 domain ----------
// DIN=128: 2 nodes per wave (half-wave = 32 lanes x 4 ch)
__global__ __launch_bounds__(256) void agg1_kernel(const void* __restrict__ X,
                                                   const bf16* __restrict__ M1,
                                                   const int* __restrict__ rowptr,
                                                   const ushort* __restrict__ ssrc,
                                                   const int* __restrict__ flag,
                                                   bf16* __restrict__ out) {
    int f32 = *flag;
    int hl = threadIdx.x & 31;
    int n = blockIdx.x * 8 + (threadIdx.x >> 5);
    int r0 = rowptr[n];
    int deg = rowptr[n + 1] - r0;
    const char* M1b = (const char*)M1;
    int boff = hl << 3;
    float s[4] = {0.f, 0.f, 0.f, 0.f}, p[4] = {0.f, 0.f, 0.f, 0.f};
    for (int base = 0; base < deg; base += 32) {
        int cnt = min(32, deg - base);
        int eo = ((base + hl < deg) ? (int)ssrc[r0 + base + hl] : 0) << 8;
        int i = 0;
        for (; i + 7 < cnt; i += 8) {
            ushort4 u[8];
#pragma unroll
            for (int k = 0; k < 8; k++) {
                int o = __shfl(eo, i + k, 32) + boff;
                u[k] = *(const ushort4*)(M1b + o);
            }
#pragma unroll
            for (int k = 0; k < 8; k++) acc4(u[k], s, p);
        }
        for (; i < cnt; i++) {
            int o = __shfl(eo, i, 32) + boff;
            acc4(*(const ushort4*)(M1b + o), s, p);
        }
    }
    float xc[4];
    ldin4(X, (size_t)n * DIN + 4 * hl, f32, xc);
    ushort4 o;
    o.x = f2bits(fmaf(LN2, p[0] / (s[0] + 1e-16f), xc[0]));
    o.y = f2bits(fmaf(LN2, p[1] / (s[1] + 1e-16f), xc[1]));
    o.z = f2bits(fmaf(LN2, p[2] / (s[2] + 1e-16f), xc[2]));
    o.w = f2bits(fmaf(LN2, p[3] / (s[3] + 1e-16f), xc[3]));
    *(ushort4*)(out + (size_t)n * DIN + 4 * hl) = o;
}

// DHID=200: 1 node per wave (lanes 0..49 x 4 ch); M2 holds (h+eps)*log2e.
__global__ __launch_bounds__(256) void agg2_kernel(const bf16* __restrict__ M2,
                                                   const int* __restrict__ rowptr,
                                                   const ushort* __restrict__ ssrc,
                                                   const ushort* __restrict__ dummy,
                                                   bf16* __restrict__ out) {
    int lane = threadIdx.x & 63;
    int n = blockIdx.x * 4 + (threadIdx.x >> 6);
    int r0 = __builtin_amdgcn_readfirstlane(rowptr[n]);
    int deg = __builtin_amdgcn_readfirstlane(rowptr[n + 1]) - r0;
    bool act = lane < 50;
    int boff = (act ? lane : 49) << 3;
    const char* M2b = (const char*)M2;
    const char* dp = (const char*)dummy;
    float s[4] = {0.f, 0.f, 0.f, 0.f}, p[4] = {0.f, 0.f, 0.f, 0.f};
    int nfull = deg >> 3;
    for (int b = 0; b < nfull; b++) {
        const ushort* ep = ssrc + r0 + (b << 3);  // uniform -> scalar loads
        ushort4 u[8];
#pragma unroll
        for (int k = 0; k < 8; k++)
            u[k] = *(const ushort4*)(M2b + (size_t)((unsigned)ep[k] * 400u) + boff);
#pragma unroll
        for (int k = 0; k < 8; k++) acc4(u[k], s, p);
    }
    int rem = deg & 7;
    if (rem) {
        const ushort* ep = ssrc + r0 + (nfull << 3);
        ushort4 u[8];
#pragma unroll
        for (int k = 0; k < 8; k++) {
            const char* rp = (k < rem) ? (M2b + (size_t)((unsigned)ep[k] * 400u)) : dp;
            u[k] = *(const ushort4*)(rp + boff);
        }
#pragma unroll
        for (int k = 0; k < 8; k++) acc4(u[k], s, p);
    }
    if (act) {
        ushort4 u = *(const ushort4*)(M2b + (size_t)n * 400 + boff);
        float vn[4] = {bits2f(u.x), bits2f(u.y), bits2f(u.z), bits2f(u.w)};
        ushort4 o;
        o.x = f2bits(LN2 * (p[0] / (s[0] + 1e-16f) + vn[0]) - 1e-7f);
        o.y = f2bits(LN2 * (p[1] / (s[1] + 1e-16f) + vn[1]) - 1e-7f);
        o.z = f2bits(LN2 * (p[2] / (s[2] + 1e-16f) + vn[2]) - 1e-7f);
        o.w = f2bits(LN2 * (p[3] / (s[3] + 1e-16f) + vn[3]) - 1e-7f);
        *(ushort4*)(out + (size_t)n * DHID + 4 * lane) = o;
    }
}

// ---------------- pipelined stripe MFMA GEMM (unchanged structure) ----------------
template <int MODE, int NT>
__global__ __launch_bounds__(256) void stripe_gemm(const bf16* __restrict__ A,
                                                   const bf16* __restrict__ Bt,
                                                   const void* __restrict__ bias,
                                                   const int* __restrict__ flag,
                                                   const float* __restrict__ sc,
                                                   const float* __restrict__ offs,
                                                   bf16* __restrict__ Out,
                                                   float* __restrict__ psum,
                                                   float* __restrict__ psq,
                                                   int M, int K, int NC, int pstride) {
    constexpr int NTW = (NT + 3) / 4;
    __shared__ short As[64][40];
    __shared__ short Bs[NT * 16][40];
    int f32 = *flag;
    int tid = threadIdx.x;
    int row0 = blockIdx.x * 64;
    int cb = blockIdx.y * NC;
    int L = tid & 63, w = tid >> 6;
    int lm = L & 15, q = L >> 4;
    int sm = tid >> 2, sk = (tid & 3) * 8;
    floatx4 acc[4][NTW];
#pragma unroll
    for (int i = 0; i < 4; i++)
#pragma unroll
        for (int j = 0; j < NTW; j++) acc[i][j] = (floatx4){0.f, 0.f, 0.f, 0.f};
    int KP = (K + 31) & ~31;

    uint4 pa = {0, 0, 0, 0};
    uint4 pb[NTW];
    float psc[8], pof[8];
    auto prefetch = [&](int k0) {
        int gm = row0 + sm, gk = k0 + sk;
        pa = (uint4){0, 0, 0, 0};
        if (gm < M && gk < K) {
            pa = *(const uint4*)(A + (size_t)gm * K + gk);
            if (MODE == 1) {
                *(float4*)&psc[0] = *(const float4*)(sc + gk);
                *(float4*)&psc[4] = *(const float4*)(sc + gk + 4);
                *(float4*)&pof[0] = *(const float4*)(offs + gk);
                *(float4*)&pof[4] = *(const float4*)(offs + gk + 4);
            }
        }
#pragma unroll
        for (int j = 0; j < NTW; j++) {
            int idx = tid + j * 256;
            int n = idx >> 2, kk = (idx & 3) * 8;
            int gk2 = k0 + kk;
            pb[j] = (uint4){0, 0, 0, 0};
            if (idx < NT * 64 && n < NC && gk2 < K)
                pb[j] = *(const uint4*)(Bt + (size_t)(cb + n) * K + gk2);
        }
    };
    prefetch(0);

    for (int k0 = 0; k0 < KP; k0 += 32) {
        {
            uint4 val = pa;
            if (MODE == 1) {
                int gm = row0 + sm, gk = k0 + sk;
                if (gm < M && gk < K) {
                    ushort us[8];
                    *(uint4*)us = val;
#pragma unroll
                    for (int j8 = 0; j8 < 8; j8++)
                        us[j8] = f2bits(fmaxf(bits2f(us[j8]) * psc[j8] + pof[j8], 0.f));
                    val = *(uint4*)us;
                }
            }
            *(uint4*)&As[sm][sk] = val;
        }
#pragma unroll
        for (int j = 0; j < NTW; j++) {
            int idx = tid + j * 256;
            if (idx < NT * 64) {
                int n = idx >> 2, kk = (idx & 3) * 8;
                *(uint4*)&Bs[n][kk] = pb[j];
            }
        }
        if (k0 + 32 < KP) prefetch(k0 + 32);
        lds_barrier();
        short8 a[4];
#pragma unroll
        for (int i = 0; i < 4; i++) a[i] = *(const short8*)&As[i * 16 + lm][q * 8];
#pragma unroll
        for (int j = 0; j < NTW; j++) {
            int tt = w * NTW + j;
            if (tt < NT) {
                short8 b = *(const short8*)&Bs[tt * 16 + lm][q * 8];
#pragma unroll
                for (int i = 0; i < 4; i++) acc[i][j] = mfma16(a[i], b, acc[i][j]);
            }
        }
        lds_barrier();
    }

#pragma unroll
    for (int j = 0; j < NTW; j++) {
        int tt = w * NTW + j;
        if (tt >= NT) continue;
        int gn = tt * 16 + lm;
        bool gok = gn < NC;
        float bb = gok ? ldin(bias, cb + gn, f32) : 0.f;
        float csum = 0.f, csq = 0.f;
#pragma unroll
        for (int i = 0; i < 4; i++) {
#pragma unroll
            for (int r = 0; r < 4; r++) {
                int gm = row0 + i * 16 + q * 4 + r;
                if (gm < M && gok) {
                    float v = acc[i][j][r] + bb;
                    if (MODE == 0) Out[(size_t)gm * pstride + cb + gn] = f2b(v);
                    if (MODE == 1)
                        Out[(size_t)gm * pstride + cb + gn] = f2b((fmaxf(v, 0.f) + 1e-7f) * LOG2E);
                    if (MODE != 1) { csum += v; csq += v * v; }
                }
            }
        }
        if (MODE != 1) {
            csum += __shfl_xor(csum, 16, 64); csq += __shfl_xor(csq, 16, 64);
            csum += __shfl_xor(csum, 32, 64); csq += __shfl_xor(csq, 32, 64);
            if (q == 0 && gok) {
                psum[(size_t)blockIdx.x * pstride + cb + gn] = csum;
                psq[(size_t)blockIdx.x * pstride + cb + gn] = csq;
            }
        }
    }
}

// two-stage stats reduction (layer 1 only now)
__global__ __launch_bounds__(256) void stats_reduce(const float* __restrict__ psum,
                                                    const float* __restrict__ psq,
                                                    float* __restrict__ bnsum,
                                                    float* __restrict__ bnsumsq,
                                                    int NB, int NC) {
    __shared__ float shs[4][64], shq[4][64];
    int cc = threadIdx.x & 63;
    int c = blockIdx.x * 64 + cc;
    int ro = threadIdx.x >> 6;
    int chunk = (NB + RSPLIT - 1) / RSPLIT;
    int b0 = blockIdx.y * chunk;
    int b1 = min(b0 + chunk, NB);
    float s = 0.f, sq = 0.f;
    if (c < NC) {
        for (int b = b0 + ro; b < b1; b += 4) {
            s += psum[(size_t)b * NC + c];
            sq += psq[(size_t)b * NC + c];
        }
    }
    shs[ro][cc] = s;
    shq[ro][cc] = sq;
    __syncthreads();
    if (threadIdx.x < 64) {
        int gc = blockIdx.x * 64 + threadIdx.x;
        if (gc < NC) {
            int t = threadIdx.x;
            float ts = shs[0][t] + shs[1][t] + shs[2][t] + shs[3][t];
            float tq = shq[0][t] + shq[1][t] + shq[2][t] + shq[3][t];
            atomicAdd(&bnsum[gc], ts);
            atomicAdd(&bnsumsq[gc], tq);
        }
    }
}

// fold BN stats (layer 1): h_norm = h*sc + off
__global__ void bn_finish(const float* __restrict__ sum, const float* __restrict__ sumsq,
                          const void* __restrict__ g, const void* __restrict__ be,
                          const int* __restrict__ flag,
                          float* __restrict__ sc, float* __restrict__ off, int C) {
    int f32 = *flag;
    int c = blockIdx.x * blockDim.x + threadIdx.x;
    if (c < C) {
        float mu = sum[c] / (float)NNODES;
        float var = fmaxf(sumsq[c] / (float)NNODES - mu * mu, 0.f);
        float rstd = rsqrtf(var + 1e-5f);
        float s = rstd * ldin(g, c, f32);
        sc[c] = s;
        off[c] = ldin(be, c, f32) - mu * s;
    }
}

// ---------------- Gram kernel: pg[b] = partial [out2|1]^T [out2|1] ----------------
// Block: 512 threads (8 waves). Wave w owns G column-tiles cj = w and w+8 (if <13).
// Per 32-node chunk: stage transposed T[208][40] (ch-major), then 16x16x32 MFMAs.
__global__ __launch_bounds__(512) void gram_kernel(const bf16* __restrict__ X,
                                                   float* __restrict__ pg) {
    __shared__ short T[GCH][GNP];
    int tid = threadIdx.x;
    int w = tid >> 6, L = tid & 63;
    int lm = L & 15, q = L >> 4;
    floatx4 acc[2][13];
#pragma unroll
    for (int c = 0; c < 2; c++)
#pragma unroll
        for (int t = 0; t < 13; t++) acc[c][t] = (floatx4){0.f, 0.f, 0.f, 0.f};

    const int chunks = (NNODES + 32 * GK_SPLIT - 1) / (32 * GK_SPLIT);  // 17
    int base0 = blockIdx.x * chunks * 32;
    for (int ch = 0; ch < chunks; ch++) {
        int nb = base0 + ch * 32;
        // stage: 1600 ushort4 (200ch x 32n / 4). node = idx&31 -> conflict-free LDS
        // writes (32 consecutive dwords/half-wave); global reads land in L1 (12.8KB chunk).
#pragma unroll
        for (int p = 0; p < 4; p++) {
            int idx = tid + p * 512;
            if (idx < 1600) {
                int nl = idx & 31, cq = idx >> 5;  // cq 0..49
                int gn = nb + nl;
                ushort4 u = {0, 0, 0, 0};
                if (gn < NNODES) u = *(const ushort4*)(X + (size_t)gn * DHID + cq * 4);
                T[cq * 4 + 0][nl] = (short)u.x;
                T[cq * 4 + 1][nl] = (short)u.y;
                T[cq * 4 + 2][nl] = (short)u.z;
                T[cq * 4 + 3][nl] = (short)u.w;
            }
        }
        if (tid < 256) {
            int nl = tid & 31, c = 200 + (tid >> 5);
            int gn = nb + nl;
            T[c][nl] = (c == 200 && gn < NNODES) ? (short)0x3F80 : (short)0;  // ones col
        }
        __syncthreads();
        short8 af[13];
#pragma unroll
        for (int t = 0; t < 13; t++) af[t] = *(const short8*)&T[t * 16 + lm][q * 8];
#pragma unroll
        for (int c = 0; c < 2; c++) {
            int cj = w + c * 8;
            if (cj < 13) {
                short8 bf = *(const short8*)&T[cj * 16 + lm][q * 8];
#pragma unroll
                for (int t = 0; t < 13; t++) acc[c][t] = mfma16(af[t], bf, acc[c][t]);
            }
        }
        __syncthreads();
    }
    float* pgb = pg + (size_t)blockIdx.x * (GCH * GCH);
#pragma unroll
    for (int c = 0; c < 2; c++) {
        int cj = w + c * 8;
        if (cj < 13) {
#pragma unroll
            for (int t = 0; t < 13; t++)
#pragma unroll
                for (int r = 0; r < 4; r++)
                    pgb[(size_t)(t * 16 + q * 4 + r) * GCH + cj * 16 + lm] = acc[c][t][r];
        }
    }
}

__global__ void greduce_kernel(const float* __restrict__ pg, float* __restrict__ G) {
    int e = blockIdx.x * 256 + threadIdx.x;
    if (e < GCH * GCH) {
        float s = 0.f;
        for (int b = 0; b < GK_SPLIT; b++) s += pg[(size_t)b * (GCH * GCH) + e];
        G[e] = s;
    }
}

// BN2 stats from Gram: for col c of h = out2*W3 + b:
//   d    = cs . w_c                (row 200 of G = colsum via ones-col)
//   mu   = d/N + b_c
//   E h2 = (w^T G w + 2 b d)/N + b^2 ;  var = E h2 - mu^2
__global__ __launch_bounds__(256) void bn2_finish(const float* __restrict__ G,
                                                  const bf16* __restrict__ Wt3,
                                                  const void* __restrict__ b1,
                                                  const void* __restrict__ g,
                                                  const void* __restrict__ be,
                                                  const int* __restrict__ flag,
                                                  float* __restrict__ sc,
                                                  float* __restrict__ off) {
    __shared__ float wl[200];
    __shared__ float red[256];
    __shared__ float dsh;
    int f32 = *flag;
    int c = blockIdx.x;  // 0..399
    int t = threadIdx.x;
    if (t < 200) wl[t] = b2f(Wt3[(size_t)c * DHID + t]);
    __syncthreads();
    float di = 0.f;
    if (t <= 200) {
        const float* Gr = G + (size_t)t * GCH;
        for (int j = 0; j < 200; j++) di = fmaf(Gr[j], wl[j], di);
    }
    red[t] = (t < 200) ? wl[t] * di : 0.f;
    if (t == 200) dsh = di;
    __syncthreads();
    for (int o = 128; o > 0; o >>= 1) {
        if (t < o) red[t] += red[t + o];
        __syncthreads();
    }
    if (t == 0) {
        float d = dsh;
        float bc = ldin(b1, c, f32);
        float mu = d / (float)NNODES + bc;
        float eh2 = (red[0] + 2.f * bc * d) / (float)NNODES + bc * bc;
        float var = fmaxf(eh2 - mu * mu, 0.f);
        float rstd = rsqrtf(var + 1e-5f);
        float s = rstd * ldin(g, c, f32);
        sc[c] = s;
        off[c] = ldin(be, c, f32) - mu * s;
    }
}

// Fused layer-2 tail, col-split (grid (NRB,2), 200 cols each)
__global__ __launch_bounds__(256) void fused_final_mfma(const bf16* __restrict__ out2,
                                                        const bf16* __restrict__ Wt3,
                                                        const void* __restrict__ b1,
                                                        const float* __restrict__ sc,
                                                        const float* __restrict__ off,
                                                        const void* __restrict__ w2,
                                                        const int* __restrict__ flag,
                                                        float* __restrict__ fscr, int M) {
    constexpr int NT = 13, NTW = 4, NCL = 200;
    __shared__ short As[64][40];
    __shared__ short Bs[NT * 16][40];
    __shared__ float red[64][2];
    int f32 = *flag;
    int tid = threadIdx.x;
    int L = tid & 63, w = tid >> 6;
    int lm = L & 15, q = L >> 4;
    int row0 = blockIdx.x * 64;
    int cb = blockIdx.y * NCL;
    int sm = tid >> 2, sk = (tid & 3) * 8;
    floatx4 acc[4][NTW];
#pragma unroll
    for (int i = 0; i < 4; i++)
#pragma unroll
        for (int j = 0; j < NTW; j++) acc[i][j] = (floatx4){0.f, 0.f, 0.f, 0.f};
    if (tid < 128) red[tid >> 1][tid & 1] = 0.f;

    uint4 pa = {0, 0, 0, 0};
    uint4 pb[NTW];
    auto prefetch = [&](int k0) {
        int gm = row0 + sm, gk = k0 + sk;
        pa = (uint4){0, 0, 0, 0};
        if (gm < M && gk < DHID) pa = *(const uint4*)(out2 + (size_t)gm * DHID + gk);
#pragma unroll
        for (int j = 0; j < NTW; j++) {
            int idx = tid + j * 256;
            int n = idx >> 2, kk = (idx & 3) * 8;
            int gk2 = k0 + kk;
            pb[j] = (uint4){0, 0, 0, 0};
            if (idx < NT * 64 && n < NCL && gk2 < DHID)
                pb[j] = *(const uint4*)(Wt3 + (size_t)(cb + n) * DHID + gk2);
        }
    };
    prefetch(0);

    for (int k0 = 0; k0 < 224; k0 += 32) {
        *(uint4*)&As[sm][sk] = pa;
#pragma unroll
        for (int j = 0; j < NTW; j++) {
            int idx = tid + j * 256;
            if (idx < NT * 64) {
                int n = idx >> 2, kk = (idx & 3) * 8;
                *(uint4*)&Bs[n][kk] = pb[j];
            }
        }
        if (k0 + 32 < 224) prefetch(k0 + 32);
        lds_barrier();
        short8 a[4];
#pragma unroll
        for (int i = 0; i < 4; i++) a[i] = *(const short8*)&As[i * 16 + lm][q * 8];
#pragma unroll
        for (int j = 0; j < NTW; j++) {
            int tt = w * NTW + j;
            if (tt < NT) {
                short8 b = *(const short8*)&Bs[tt * 16 + lm][q * 8];
#pragma unroll
                for (int i = 0; i < 4; i++) acc[i][j] = mfma16(a[i], b, acc[i][j]);
            }
        }
        lds_barrier();
    }

    float s0[4][4], s1[4][4];
#pragma unroll
    for (int i = 0; i < 4; i++)
#pragma unroll
        for (int r = 0; r < 4; r++) { s0[i][r] = 0.f; s1[i][r] = 0.f; }
#pragma unroll
    for (int j = 0; j < NTW; j++) {
        int tt = w * NTW + j;
        if (tt >= NT) continue;
        int gn = tt * 16 + lm;
        if (gn < NCL) {
            int gg = cb + gn;
            float bb = ldin(b1, gg, f32);
            float scv = sc[gg], ofv = off[gg];
            float w20 = ldin(w2, 2 * gg, f32), w21 = ldin(w2, 2 * gg + 1, f32);
#pragma unroll
            for (int i = 0; i < 4; i++)
#pragma unroll
                for (int r = 0; r < 4; r++) {
                    float vn = fmaxf((acc[i][j][r] + bb) * scv + ofv, 0.f);
                    s0[i][r] = fmaf(vn, w20, s0[i][r]);
                    s1[i][r] = fmaf(vn, w21, s1[i][r]);
                }
        }
    }
#pragma unroll
    for (int d = 1; d < 16; d <<= 1) {
#pragma unroll
        for (int i = 0; i < 4; i++)
#pragma unroll
            for (int r = 0; r < 4; r++) {
                s0[i][r] += __shfl_xor(s0[i][r], d, 64);
                s1[i][r] += __shfl_xor(s1[i][r], d, 64);
            }
    }
    if (lm == 0) {
#pragma unroll
        for (int i = 0; i < 4; i++)
#pragma unroll
            for (int r = 0; r < 4; r++) {
                atomicAdd(&red[i * 16 + q * 4 + r][0], s0[i][r]);
                atomicAdd(&red[i * 16 + q * 4 + r][1], s1[i][r]);
            }
    }
    __syncthreads();
    if (tid < 64) {
        int gm = row0 + tid;
        if (gm < M) {
            fscr[(size_t)gm * 4 + blockIdx.y * 2 + 0] = red[tid][0];
            fscr[(size_t)gm * 4 + blockIdx.y * 2 + 1] = red[tid][1];
        }
    }
}

// combine the two col-half partials: out = relu(p0+p1+b2)
__global__ void final_combine(const float* __restrict__ fscr, const void* __restrict__ b2,
                              const int* __restrict__ flag, void* __restrict__ outp, int M) {
    int f32 = *flag;
    int n = blockIdx.x * 256 + threadIdx.x;
    if (n < M) {
        float v0 = fmaxf(fscr[(size_t)n * 4 + 0] + fscr[(size_t)n * 4 + 2] + ldin(b2, 0, f32), 0.f);
        float v1 = fmaxf(fscr[(size_t)n * 4 + 1] + fscr[(size_t)n * 4 + 3] + ldin(b2, 1, f32), 0.f);
        if (f32) {
            ((float*)outp)[2 * n] = v0;
            ((float*)outp)[2 * n + 1] = v1;
        } else {
            ((bf16*)outp)[2 * n] = f2b(v0);
            ((bf16*)outp)[2 * n + 1] = f2b(v1);
        }
    }
}

extern "C" void kernel_launch(void* const* d_in, const int* in_sizes, int n_in,
                              void* d_out, int out_size, void* d_ws, size_t ws_size,
                              hipStream_t stream) {
    const void* x = d_in[0];
    const int* ei = (const int*)d_in[1];
    const void* c1_w1 = d_in[2];
    const void* c1_b1 = d_in[3];
    const void* c1_g = d_in[4];
    const void* c1_be = d_in[5];
    const void* c1_w2 = d_in[6];
    const void* c1_b2 = d_in[7];
    const void* c2_w1 = d_in[8];
    const void* c2_b1 = d_in[9];
    const void* c2_g = d_in[10];
    const void* c2_be = d_in[11];
    const void* c2_w2 = d_in[12];
    const void* c2_b2 = d_in[13];

    const int* src = ei;
    const int* dst = ei + NEDGES;

    // -------- workspace layout (liveness-overlaid, ~49.4 MB) --------
    uint8_t* w = (uint8_t*)d_ws;
    int* rowptr = (int*)(w + 0);
    int* counts = (int*)(w + 204800);
    int* cursor = (int*)(w + 409600);
    bf16* wT1 = (bf16*)(w + 204800);        // overlays counts (written post-scan)
    bf16* wT2 = (bf16*)(w + 270336);
    bf16* wT3 = (bf16*)(w + 409600);        // overlays cursor (written post-scatter)
    ushort* ssrc = (ushort*)(w + 614400);   // 1.6MB (ushort: NNODES < 65536)
    float* bnbuf = (float*)(w + 3814400);
    float* sum1 = bnbuf, *sumsq1 = bnbuf + 256;
    float* sc1 = bnbuf + 1312, *off1 = bnbuf + 1568;
    float* sc2 = bnbuf + 1824, *off2 = bnbuf + 2224;
    int* flag_in = (int*)(bnbuf + 2624);
    int* blocksums = (int*)(bnbuf + 2640);
    ushort* dummyrow = (ushort*)(bnbuf + 2840);
    uint8_t* bufA = w + 3830784;   // 20MB: out1 -> (ps1/pq1) -> h1 -> pg/G -> fscr
    uint8_t* bufB = w + 23830784;  // 25.6MB: M1 -> t1 -> out2
    bf16* out1 = (bf16*)bufA;
    bf16* h1 = (bf16*)bufA;
    float* fscr = (float*)bufA;                       // live only after greduce
    float* pg = (float*)bufA;                         // 96*208*208*4 = 16.6MB (h1 dead)
    float* Gm = (float*)(bufA + 17000000);            // 173KB final Gram
    bf16* M1 = (bf16*)bufB;
    bf16* t1 = (bf16*)bufB;
    bf16* out2 = (bf16*)bufB;
    float* ps1 = (float*)(bufA + 12800000);
    float* pq1 = ps1 + (size_t)NRB * MID1;

    hipMemsetAsync(counts, 0, NNODES * sizeof(int), stream);
    hipMemsetAsync(bnbuf, 0, 1312 * sizeof(float), stream);  // layer-1 atomics target

    // CSR build
    hist_kernel<<<(NEDGES + 255) / 256, 256, 0, stream>>>(dst, counts, c1_g, flag_in);
    scanA_kernel<<<SCAN_NB, 256, 0, stream>>>(counts, rowptr, blocksums);
    scanC_kernel<<<SCAN_NB, 256, 0, stream>>>(rowptr, cursor, blocksums);
    scatter_kernel<<<(NEDGES + 255) / 256, 256, 0, stream>>>(src, dst, cursor, ssrc);

    // weight transposes + M1 msg table + dummy row
    prep_kernel<<<(NNODES * DIN / 4 + 255) / 256, 256, 0, stream>>>(
        c1_w1, wT1, c1_w2, wT2, c2_w1, wT3, x, M1, dummyrow, flag_in);

    // ----- layer 1 -----
    agg1_kernel<<<NNODES / 8, 256, 0, stream>>>(x, M1, rowptr, ssrc, flag_in, out1);
    stripe_gemm<0, 16><<<dim3(NRB, 1), 256, 0, stream>>>(out1, wT1, c1_b1, flag_in,
                                                         nullptr, nullptr, t1, ps1, pq1,
                                                         NNODES, DIN, MID1, MID1);
    stats_reduce<<<dim3((MID1 + 63) / 64, RSPLIT), 256, 0, stream>>>(ps1, pq1, sum1, sumsq1,
                                                                     NRB, MID1);
    bn_finish<<<1, 256, 0, stream>>>(sum1, sumsq1, c1_g, c1_be, flag_in, sc1, off1, MID1);
    stripe_gemm<1, 13><<<dim3(NRB, 1), 256, 0, stream>>>(t1, wT2, c1_b2, flag_in,
                                                         sc1, off1, h1, nullptr, nullptr,
                                                         NNODES, MID1, DHID, DHID);

    // ----- layer 2 -----
    agg2_kernel<<<NNODES / 4, 256, 0, stream>>>(h1, rowptr, ssrc, dummyrow, out2);
    // BN2 stats via Gram algebra (replaces the 8-GFLOP stats GEMM):
    gram_kernel<<<GK_SPLIT, 512, 0, stream>>>(out2, pg);
    greduce_kernel<<<(GCH * GCH + 255) / 256, 256, 0, stream>>>(pg, Gm);
    bn2_finish<<<MID2, 256, 0, stream>>>(Gm, wT3, c2_b1, c2_g, c2_be, flag_in, sc2, off2);
    fused_final_mfma<<<dim3(NRB, 2), 256, 0, stream>>>(out2, wT3, c2_b1, sc2, off2,
                                                       c2_w2, flag_in, fscr, NNODES);
    final_combine<<<(NNODES + 255) / 256, 256, 0, stream>>>(fscr, c2_b2, flag_in,
                                                            d_out, NNODES);
}

// Round 4
// 428.252 us; speedup vs baseline: 1.2455x; 1.0331x over previous
//
#include <hip/hip_runtime.h>
#include <hip/hip_bf16.h>
#include <stdint.h>

#define NNODES 50000
#define NEDGES 800000
#define DIN 128
#define DHID 200
#define MID1 256
#define MID2 400
#define SCAN_NB ((NNODES + 255) / 256)  // 196
#define NBB ((NNODES + 127) / 128)      // 391 row-blocks (128 rows, 8 waves)
#define RSPLIT 12
#define LOG2E 1.4426950408889634f
#define LN2 0.6931471805599453f
// Gram (layer-2 BN stats): G = [out2 | 1]^T [out2 | 1], 208x208 padded
#define GK_SPLIT 96
#define GCH 208
#define GNP 40

typedef __hip_bfloat16 bf16;
typedef __attribute__((ext_vector_type(8))) short short8;
typedef __attribute__((ext_vector_type(4))) float floatx4;
typedef unsigned short ushort;

__device__ __forceinline__ float b2f(bf16 v) { return __bfloat162float(v); }
__device__ __forceinline__ bf16 f2b(float v) { return __float2bfloat16(v); }
__device__ __forceinline__ float bits2f(ushort b) {
    unsigned u = ((unsigned)b) << 16;
    return __uint_as_float(u);
}
__device__ __forceinline__ ushort f2bits(float f) {
    bf16 h = __float2bfloat16(f);
    return *(ushort*)&h;
}
__device__ __forceinline__ float ldin(const void* p, size_t i, int f32) {
    return f32 ? ((const float*)p)[i] : __bfloat162float(((const bf16*)p)[i]);
}
__device__ __forceinline__ void ldin4(const void* p, size_t i, int f32, float* v) {
    if (f32) {
        float4 f = *(const float4*)((const float*)p + i);
        v[0] = f.x; v[1] = f.y; v[2] = f.z; v[3] = f.w;
    } else {
        ushort4 u = *(const ushort4*)((const bf16*)p + i);
        v[0] = bits2f(u.x); v[1] = bits2f(u.y); v[2] = bits2f(u.z); v[3] = bits2f(u.w);
    }
}
__device__ __forceinline__ float fexp2(float x) {
#if __has_builtin(__builtin_amdgcn_exp2f)
    return __builtin_amdgcn_exp2f(x);
#else
    return exp2f(x);
#endif
}
__device__ __forceinline__ floatx4 mfma16(short8 a, short8 b, floatx4 c) {
    return __builtin_amdgcn_mfma_f32_16x16x32_bf16(a, b, c, 0, 0, 0);
}
// exp2-domain softmax accumulate over 4 packed channels
__device__ __forceinline__ void acc4(ushort4 u, float* s, float* p) {
    ushort uu[4];
    *(ushort4*)uu = u;
#pragma unroll
    for (int c = 0; c < 4; c++) {
        float v = bits2f(uu[c]);
        float ee = fexp2(v);
        s[c] += ee;
        p[c] = fmaf(v, ee, p[c]);
    }
}

// ---------------- CSR build ----------------
__global__ void hist_kernel(const int* __restrict__ dst, int* __restrict__ counts,
                            const void* __restrict__ g, int* __restrict__ flag) {
    int e = blockIdx.x * blockDim.x + threadIdx.x;
    if (e == 0)
        *flag = (((const unsigned*)g)[0] == 0x3F800000u) ? 1 : 0;
    if (e < NEDGES) atomicAdd(&counts[dst[e]], 1);
}

__global__ __launch_bounds__(256) void scanA_kernel(const int* __restrict__ counts,
                                                    int* __restrict__ rowptr,
                                                    int* __restrict__ blocksums) {
    __shared__ int sh[256];
    int t = threadIdx.x, b = blockIdx.x;
    int i = b * 256 + t;
    int v = (i < NNODES) ? counts[i] : 0;
    sh[t] = v;
    __syncthreads();
#pragma unroll
    for (int off = 1; off < 256; off <<= 1) {
        int o = (t >= off) ? sh[t - off] : 0;
        __syncthreads();
        sh[t] += o;
        __syncthreads();
    }
    if (i < NNODES) rowptr[i] = sh[t] - v;
    if (t == 255) blocksums[b] = sh[255];
}

__global__ __launch_bounds__(256) void scanC_kernel(int* __restrict__ rowptr,
                                                    int* __restrict__ cursor,
                                                    const int* __restrict__ blocksums) {
    __shared__ int sh[256];
    int t = threadIdx.x, b = blockIdx.x;
    sh[t] = (t < SCAN_NB) ? blocksums[t] : 0;
    __syncthreads();
#pragma unroll
    for (int off = 1; off < 256; off <<= 1) {
        int o = (t >= off) ? sh[t - off] : 0;
        __syncthreads();
        sh[t] += o;
        __syncthreads();
    }
    int boff = (b > 0) ? sh[b - 1] : 0;
    int i = b * 256 + t;
    if (i < NNODES) {
        int r = rowptr[i] + boff;
        rowptr[i] = r;
        cursor[i] = r;
    }
    if (i == 0) rowptr[NNODES] = NEDGES;
}

__global__ void scatter_kernel(const int* __restrict__ src, const int* __restrict__ dst,
                               int* __restrict__ cursor, int* __restrict__ ssrc) {
    int e = blockIdx.x * blockDim.x + threadIdx.x;
    if (e < NEDGES) {
        int p = atomicAdd(&cursor[dst[e]], 1);
        ssrc[p] = src[e];
    }
}

// ---------------- prep: 3 weight transposes + M1 exp2-domain msg table ----------------
#define TW (DIN * MID1 + MID1 * DHID + DHID * MID2)  // 163968
__global__ __launch_bounds__(256) void prep_kernel(const void* __restrict__ W1, bf16* __restrict__ Wt1,
                                                   const void* __restrict__ W2, bf16* __restrict__ Wt2,
                                                   const void* __restrict__ W3, bf16* __restrict__ Wt3,
                                                   const void* __restrict__ X, bf16* __restrict__ M1,
                                                   ushort* __restrict__ dummy,
                                                   const int* __restrict__ flag) {
    const int S1 = DIN * MID1, S2 = MID1 * DHID;
    int f32 = *flag;
    int idx = blockIdx.x * 256 + threadIdx.x;
    if (idx < TW) {
        const void* W;
        bf16* Wt;
        int K, N, li;
        if (idx < S1) { W = W1; Wt = Wt1; K = DIN; N = MID1; li = idx; }
        else if (idx < S1 + S2) { W = W2; Wt = Wt2; K = MID1; N = DHID; li = idx - S1; }
        else { W = W3; Wt = Wt3; K = DHID; N = MID2; li = idx - S1 - S2; }
        int k = li / N, n = li - k * N;
        Wt[(size_t)n * K + k] = f2b(ldin(W, li, f32));
    }
    if (idx < DHID) dummy[idx] = 0xC300;  // bf16(-128): exp2 -> 0, softmax no-op
    int i = idx * 4;
    if (i < NNODES * DIN) {
        float v[4];
        ldin4(X, i, f32, v);
        ushort4 o;
        o.x = f2bits((fmaxf(v[0], 0.f) + 1e-7f) * LOG2E);
        o.y = f2bits((fmaxf(v[1], 0.f) + 1e-7f) * LOG2E);
        o.z = f2bits((fmaxf(v[2], 0.f) + 1e-7f) * LOG2E);
        o.w = f2bits((fmaxf(v[3], 0.f) + 1e-7f) * LOG2E);
        *(ushort4*)(M1 + i) = o;
    }
}

// ---------------- aggregation ----------
// DIN=128: 2 nodes per wave (half-wave = 32 lanes x 4 ch)
__global__ __launch_bounds__(256) void agg1_kernel(const void* __restrict__ X,
                                                   const bf16* __restrict__ M1,
                                                   const int* __restrict__ rowptr,
                                                   const int* __restrict__ ssrc,
                                                   const int* __restrict__ flag,
                                                   bf16* __restrict__ out) {
    int f32 = *flag;
    int hl = threadIdx.x & 31;
    int n = blockIdx.x * 8 + (threadIdx.x >> 5);
    int r0 = rowptr[n];
    int deg = rowptr[n + 1] - r0;
    const char* M1b = (const char*)M1;
    int boff = hl << 3;
    float s[4] = {0.f, 0.f, 0.f, 0.f}, p[4] = {0.f, 0.f, 0.f, 0.f};
    for (int base = 0; base < deg; base += 32) {
        int cnt = min(32, deg - base);
        int eo = ((base + hl < deg) ? ssrc[r0 + base + hl] : 0) << 8;
        int i = 0;
        for (; i + 7 < cnt; i += 8) {
            ushort4 u[8];
#pragma unroll
            for (int k = 0; k < 8; k++) {
                int o = __shfl(eo, i + k, 32) + boff;
                u[k] = *(const ushort4*)(M1b + o);
            }
#pragma unroll
            for (int k = 0; k < 8; k++) acc4(u[k], s, p);
        }
        for (; i < cnt; i++) {
            int o = __shfl(eo, i, 32) + boff;
            acc4(*(const ushort4*)(M1b + o), s, p);
        }
    }
    float xc[4];
    ldin4(X, (size_t)n * DIN + 4 * hl, f32, xc);
    ushort4 o;
    o.x = f2bits(fmaf(LN2, p[0] / (s[0] + 1e-16f), xc[0]));
    o.y = f2bits(fmaf(LN2, p[1] / (s[1] + 1e-16f), xc[1]));
    o.z = f2bits(fmaf(LN2, p[2] / (s[2] + 1e-16f), xc[2]));
    o.w = f2bits(fmaf(LN2, p[3] / (s[3] + 1e-16f), xc[3]));
    *(ushort4*)(out + (size_t)n * DIN + 4 * hl) = o;
}

// DHID=200: 1 node per wave (lanes 0..49 x 4 ch); M2 holds (h+eps)*log2e.
// Wave-uniform edge indices -> scalar loads; remainder via dummy(-128) row.
__global__ __launch_bounds__(256) void agg2_kernel(const bf16* __restrict__ M2,
                                                   const int* __restrict__ rowptr,
                                                   const int* __restrict__ ssrc,
                                                   const ushort* __restrict__ dummy,
                                                   bf16* __restrict__ out) {
    int lane = threadIdx.x & 63;
    int n = blockIdx.x * 4 + (threadIdx.x >> 6);
    int r0 = __builtin_amdgcn_readfirstlane(rowptr[n]);
    int deg = __builtin_amdgcn_readfirstlane(rowptr[n + 1]) - r0;
    bool act = lane < 50;
    int boff = (act ? lane : 49) << 3;
    const char* M2b = (const char*)M2;
    const char* dp = (const char*)dummy;
    float s[4] = {0.f, 0.f, 0.f, 0.f}, p[4] = {0.f, 0.f, 0.f, 0.f};
    int nfull = deg >> 3;
    for (int b = 0; b < nfull; b++) {
        const int* ep = ssrc + r0 + (b << 3);  // uniform -> s_load
        ushort4 u[8];
#pragma unroll
        for (int k = 0; k < 8; k++)
            u[k] = *(const ushort4*)(M2b + (size_t)((unsigned)ep[k] * 400u) + boff);
#pragma unroll
        for (int k = 0; k < 8; k++) acc4(u[k], s, p);
    }
    int rem = deg & 7;
    if (rem) {
        const int* ep = ssrc + r0 + (nfull << 3);
        ushort4 u[8];
#pragma unroll
        for (int k = 0; k < 8; k++) {
            const char* rp = (k < rem) ? (M2b + (size_t)((unsigned)ep[k] * 400u)) : dp;
            u[k] = *(const ushort4*)(rp + boff);
        }
#pragma unroll
        for (int k = 0; k < 8; k++) acc4(u[k], s, p);
    }
    if (act) {
        ushort4 u = *(const ushort4*)(M2b + (size_t)n * 400 + boff);
        float vn[4] = {bits2f(u.x), bits2f(u.y), bits2f(u.z), bits2f(u.w)};
        ushort4 o;
        o.x = f2bits(LN2 * (p[0] / (s[0] + 1e-16f) + vn[0]) - 1e-7f);
        o.y = f2bits(LN2 * (p[1] / (s[1] + 1e-16f) + vn[1]) - 1e-7f);
        o.z = f2bits(LN2 * (p[2] / (s[2] + 1e-16f) + vn[2]) - 1e-7f);
        o.w = f2bits(LN2 * (p[3] / (s[3] + 1e-16f) + vn[3]) - 1e-7f);
        *(ushort4*)(out + (size_t)n * DHID + 4 * lane) = o;
    }
}

// ---------------- B-stationary barrier-free GEMM ----------------
// Whole B (NCOL x KK, padded) staged in LDS once; ONE barrier; then each wave
// owns 16 rows x NCOL with all A-fragments prefetched to registers and a fully
// unrolled ds_read+mfma stream with NO barriers (waves slip freely -> TLP hides
// latency; this attacks the 55us lockstep floor of the old stripe_gemm).
// MODE 0: G1  out=t1 raw + per-wave psum/psq         (NCOL=256, KK=128)
// MODE 1: G2  A-transform relu(a*sc+off); msg-store  (NCOL=100 x2, KK=256)
// MODE 2: FF  BN2+relu+w2 row-reduce -> fscr         (NCOL=100 x4, KK=200)
template <int MODE, int NT, int KK, int NCOL>
__global__ __launch_bounds__(512, 4) void bgemm(const bf16* __restrict__ A,
                                                const bf16* __restrict__ Bt,
                                                const void* __restrict__ bias,
                                                const int* __restrict__ flag,
                                                const float* __restrict__ sc,
                                                const float* __restrict__ offs,
                                                const void* __restrict__ w2,
                                                bf16* __restrict__ Out, int ostride,
                                                float* __restrict__ psum,
                                                float* __restrict__ psq,
                                                float* __restrict__ fscr, int M) {
    constexpr int KP = (KK + 31) & ~31;
    constexpr int KS = KP / 32;
    constexpr int KV8 = KP / 8;
    __shared__ short Bs[NT * 16][KP + 8];
    int f32 = *flag;
    int tid = threadIdx.x;
    int cb = blockIdx.y * NCOL;

    // stage whole B tile (zero-fill pads)
    for (int idx = tid; idx < NT * 16 * KV8; idx += 512) {
        int col = idx / KV8, kq = (idx - col * KV8) * 8;
        uint4 v = {0, 0, 0, 0};
        if (col < NCOL && kq < KK) v = *(const uint4*)(Bt + (size_t)(cb + col) * KK + kq);
        *(uint4*)&Bs[col][kq] = v;
    }
    __syncthreads();

    int w = tid >> 6, L = tid & 63;
    int lm = L & 15, q = L >> 4;
    int rw = blockIdx.x * 128 + w * 16;
    int ar = rw + lm;
    bool rok = ar < M;

    // prefetch ALL A fragments for this wave's 16 rows (4-8 16B loads in flight)
    uint4 af[KS];
#pragma unroll
    for (int s = 0; s < KS; s++) {
        int k = s * 32 + q * 8;
        af[s] = (uint4){0, 0, 0, 0};
        if (rok && k + 8 <= KK) af[s] = *(const uint4*)(A + (size_t)ar * KK + k);
    }

    floatx4 acc[NT];
#pragma unroll
    for (int t = 0; t < NT; t++) acc[t] = (floatx4){0.f, 0.f, 0.f, 0.f};

#pragma unroll
    for (int s = 0; s < KS; s++) {
        short8 as;
        if (MODE == 1) {
            int ch = s * 32 + q * 8;
            float4 sA = *(const float4*)(sc + ch), sB = *(const float4*)(sc + ch + 4);
            float4 oA = *(const float4*)(offs + ch), oB = *(const float4*)(offs + ch + 4);
            float scv[8] = {sA.x, sA.y, sA.z, sA.w, sB.x, sB.y, sB.z, sB.w};
            float ofv[8] = {oA.x, oA.y, oA.z, oA.w, oB.x, oB.y, oB.z, oB.w};
            ushort us[8];
            *(uint4*)us = af[s];
#pragma unroll
            for (int j = 0; j < 8; j++)
                us[j] = f2bits(fmaxf(fmaf(bits2f(us[j]), scv[j], ofv[j]), 0.f));
            as = *(short8*)us;
        } else {
            as = *(short8*)&af[s];
        }
#pragma unroll
        for (int t = 0; t < NT; t++) {
            short8 bf = *(const short8*)&Bs[t * 16 + lm][s * 32 + q * 8];
            acc[t] = mfma16(as, bf, acc[t]);
        }
    }

    if (MODE == 0) {
#pragma unroll
        for (int t = 0; t < NT; t++) {
            int col = t * 16 + lm;
            float bb = ldin(bias, col, f32);
            float cs = 0.f, cq = 0.f;
#pragma unroll
            for (int r = 0; r < 4; r++) {
                int gm = rw + q * 4 + r;
                if (gm < M) {
                    float v = acc[t][r] + bb;
                    Out[(size_t)gm * ostride + col] = f2b(v);
                    cs += v;
                    cq += v * v;
                }
            }
            cs += __shfl_xor(cs, 16, 64); cq += __shfl_xor(cq, 16, 64);
            cs += __shfl_xor(cs, 32, 64); cq += __shfl_xor(cq, 32, 64);
            if (q == 0) {
                psum[(size_t)(blockIdx.x * 8 + w) * (NT * 16) + col] = cs;
                psq[(size_t)(blockIdx.x * 8 + w) * (NT * 16) + col] = cq;
            }
        }
    }
    if (MODE == 1) {
#pragma unroll
        for (int t = 0; t < NT; t++) {
            int col = t * 16 + lm;
            if (col < NCOL) {
                int gg = cb + col;
                float bb = ldin(bias, gg, f32);
#pragma unroll
                for (int r = 0; r < 4; r++) {
                    int gm = rw + q * 4 + r;
                    if (gm < M) {
                        float v = acc[t][r] + bb;
                        Out[(size_t)gm * ostride + gg] = f2b((fmaxf(v, 0.f) + 1e-7f) * LOG2E);
                    }
                }
            }
        }
    }
    if (MODE == 2) {
        float s0[4] = {0.f, 0.f, 0.f, 0.f}, s1[4] = {0.f, 0.f, 0.f, 0.f};
#pragma unroll
        for (int t = 0; t < NT; t++) {
            int col = t * 16 + lm;
            if (col < NCOL) {
                int gg = cb + col;
                float bb = ldin(bias, gg, f32);
                float scv = sc[gg], ofv = offs[gg];
                float w20 = ldin(w2, 2 * gg, f32), w21 = ldin(w2, 2 * gg + 1, f32);
#pragma unroll
                for (int r = 0; r < 4; r++) {
                    float vn = fmaxf((acc[t][r] + bb) * scv + ofv, 0.f);
                    s0[r] = fmaf(vn, w20, s0[r]);
                    s1[r] = fmaf(vn, w21, s1[r]);
                }
            }
        }
#pragma unroll
        for (int d = 1; d < 16; d <<= 1) {
#pragma unroll
            for (int r = 0; r < 4; r++) {
                s0[r] += __shfl_xor(s0[r], d, 64);
                s1[r] += __shfl_xor(s1[r], d, 64);
            }
        }
        if (lm == 0) {
#pragma unroll
            for (int r = 0; r < 4; r++) {
                int gm = rw + q * 4 + r;
                if (gm < M) {
                    fscr[(size_t)gm * 8 + blockIdx.y * 2 + 0] = s0[r];
                    fscr[(size_t)gm * 8 + blockIdx.y * 2 + 1] = s1[r];
                }
            }
        }
    }
}

// two-stage stats reduction (layer 1)
__global__ __launch_bounds__(256) void stats_reduce(const float* __restrict__ psum,
                                                    const float* __restrict__ psq,
                                                    float* __restrict__ bnsum,
                                                    float* __restrict__ bnsumsq,
                                                    int NB, int NC) {
    __shared__ float shs[4][64], shq[4][64];
    int cc = threadIdx.x & 63;
    int c = blockIdx.x * 64 + cc;
    int ro = threadIdx.x >> 6;
    int chunk = (NB + RSPLIT - 1) / RSPLIT;
    int b0 = blockIdx.y * chunk;
    int b1 = min(b0 + chunk, NB);
    float s = 0.f, sq = 0.f;
    if (c < NC) {
        for (int b = b0 + ro; b < b1; b += 4) {
            s += psum[(size_t)b * NC + c];
            sq += psq[(size_t)b * NC + c];
        }
    }
    shs[ro][cc] = s;
    shq[ro][cc] = sq;
    __syncthreads();
    if (threadIdx.x < 64) {
        int gc = blockIdx.x * 64 + threadIdx.x;
        if (gc < NC) {
            int t = threadIdx.x;
            float ts = shs[0][t] + shs[1][t] + shs[2][t] + shs[3][t];
            float tq = shq[0][t] + shq[1][t] + shq[2][t] + shq[3][t];
            atomicAdd(&bnsum[gc], ts);
            atomicAdd(&bnsumsq[gc], tq);
        }
    }
}

// fold BN stats (layer 1): h_norm = h*sc + off
__global__ void bn_finish(const float* __restrict__ sum, const float* __restrict__ sumsq,
                          const void* __restrict__ g, const void* __restrict__ be,
                          const int* __restrict__ flag,
                          float* __restrict__ sc, float* __restrict__ off, int C) {
    int f32 = *flag;
    int c = blockIdx.x * blockDim.x + threadIdx.x;
    if (c < C) {
        float mu = sum[c] / (float)NNODES;
        float var = fmaxf(sumsq[c] / (float)NNODES - mu * mu, 0.f);
        float rstd = rsqrtf(var + 1e-5f);
        float s = rstd * ldin(g, c, f32);
        sc[c] = s;
        off[c] = ldin(be, c, f32) - mu * s;
    }
}

// ---------------- Gram kernel (layer-2 BN stats) ----------------
__global__ __launch_bounds__(512) void gram_kernel(const bf16* __restrict__ X,
                                                   float* __restrict__ pg) {
    __shared__ short T[GCH][GNP];
    int tid = threadIdx.x;
    int w = tid >> 6, L = tid & 63;
    int lm = L & 15, q = L >> 4;
    floatx4 acc[2][13];
#pragma unroll
    for (int c = 0; c < 2; c++)
#pragma unroll
        for (int t = 0; t < 13; t++) acc[c][t] = (floatx4){0.f, 0.f, 0.f, 0.f};

    const int chunks = (NNODES + 32 * GK_SPLIT - 1) / (32 * GK_SPLIT);  // 17
    int base0 = blockIdx.x * chunks * 32;
    for (int ch = 0; ch < chunks; ch++) {
        int nb = base0 + ch * 32;
#pragma unroll
        for (int p = 0; p < 4; p++) {
            int idx = tid + p * 512;
            if (idx < 1600) {
                int nl = idx & 31, cq = idx >> 5;
                int gn = nb + nl;
                ushort4 u = {0, 0, 0, 0};
                if (gn < NNODES) u = *(const ushort4*)(X + (size_t)gn * DHID + cq * 4);
                T[cq * 4 + 0][nl] = (short)u.x;
                T[cq * 4 + 1][nl] = (short)u.y;
                T[cq * 4 + 2][nl] = (short)u.z;
                T[cq * 4 + 3][nl] = (short)u.w;
            }
        }
        if (tid < 256) {
            int nl = tid & 31, c = 200 + (tid >> 5);
            int gn = nb + nl;
            T[c][nl] = (c == 200 && gn < NNODES) ? (short)0x3F80 : (short)0;
        }
        __syncthreads();
        short8 af[13];
#pragma unroll
        for (int t = 0; t < 13; t++) af[t] = *(const short8*)&T[t * 16 + lm][q * 8];
#pragma unroll
        for (int c = 0; c < 2; c++) {
            int cj = w + c * 8;
            if (cj < 13) {
                short8 bf = *(const short8*)&T[cj * 16 + lm][q * 8];
#pragma unroll
                for (int t = 0; t < 13; t++) acc[c][t] = mfma16(af[t], bf, acc[c][t]);
            }
        }
        __syncthreads();
    }
    float* pgb = pg + (size_t)blockIdx.x * (GCH * GCH);
#pragma unroll
    for (int c = 0; c < 2; c++) {
        int cj = w + c * 8;
        if (cj < 13) {
#pragma unroll
            for (int t = 0; t < 13; t++)
#pragma unroll
                for (int r = 0; r < 4; r++)
                    pgb[(size_t)(t * 16 + q * 4 + r) * GCH + cj * 16 + lm] = acc[c][t][r];
        }
    }
}

__global__ void greduce_kernel(const float* __restrict__ pg, float* __restrict__ G) {
    int e = blockIdx.x * 256 + threadIdx.x;
    if (e < GCH * GCH) {
        float s = 0.f;
        for (int b = 0; b < GK_SPLIT; b++) s += pg[(size_t)b * (GCH * GCH) + e];
        G[e] = s;
    }
}

// BN2 stats from Gram
__global__ __launch_bounds__(256) void bn2_finish(const float* __restrict__ G,
                                                  const bf16* __restrict__ Wt3,
                                                  const void* __restrict__ b1,
                                                  const void* __restrict__ g,
                                                  const void* __restrict__ be,
                                                  const int* __restrict__ flag,
                                                  float* __restrict__ sc,
                                                  float* __restrict__ off) {
    __shared__ float wl[200];
    __shared__ float red[256];
    __shared__ float dsh;
    int f32 = *flag;
    int c = blockIdx.x;
    int t = threadIdx.x;
    if (t < 200) wl[t] = b2f(Wt3[(size_t)c * DHID + t]);
    __syncthreads();
    float di = 0.f;
    if (t <= 200) {
        const float* Gr = G + (size_t)t * GCH;
        for (int j = 0; j < 200; j++) di = fmaf(Gr[j], wl[j], di);
    }
    red[t] = (t < 200) ? wl[t] * di : 0.f;
    if (t == 200) dsh = di;
    __syncthreads();
    for (int o = 128; o > 0; o >>= 1) {
        if (t < o) red[t] += red[t + o];
        __syncthreads();
    }
    if (t == 0) {
        float d = dsh;
        float bc = ldin(b1, c, f32);
        float mu = d / (float)NNODES + bc;
        float eh2 = (red[0] + 2.f * bc * d) / (float)NNODES + bc * bc;
        float var = fmaxf(eh2 - mu * mu, 0.f);
        float rstd = rsqrtf(var + 1e-5f);
        float s = rstd * ldin(g, c, f32);
        sc[c] = s;
        off[c] = ldin(be, c, f32) - mu * s;
    }
}

// combine the four col-quarter partials: out = relu(sum + b2)
__global__ void final_combine(const float* __restrict__ fscr, const void* __restrict__ b2,
                              const int* __restrict__ flag, void* __restrict__ outp, int M) {
    int f32 = *flag;
    int n = blockIdx.x * 256 + threadIdx.x;
    if (n < M) {
        const float* f = fscr + (size_t)n * 8;
        float v0 = fmaxf(f[0] + f[2] + f[4] + f[6] + ldin(b2, 0, f32), 0.f);
        float v1 = fmaxf(f[1] + f[3] + f[5] + f[7] + ldin(b2, 1, f32), 0.f);
        if (f32) {
            ((float*)outp)[2 * n] = v0;
            ((float*)outp)[2 * n + 1] = v1;
        } else {
            ((bf16*)outp)[2 * n] = f2b(v0);
            ((bf16*)outp)[2 * n + 1] = f2b(v1);
        }
    }
}

extern "C" void kernel_launch(void* const* d_in, const int* in_sizes, int n_in,
                              void* d_out, int out_size, void* d_ws, size_t ws_size,
                              hipStream_t stream) {
    const void* x = d_in[0];
    const int* ei = (const int*)d_in[1];
    const void* c1_w1 = d_in[2];
    const void* c1_b1 = d_in[3];
    const void* c1_g = d_in[4];
    const void* c1_be = d_in[5];
    const void* c1_w2 = d_in[6];
    const void* c1_b2 = d_in[7];
    const void* c2_w1 = d_in[8];
    const void* c2_b1 = d_in[9];
    const void* c2_g = d_in[10];
    const void* c2_be = d_in[11];
    const void* c2_w2 = d_in[12];
    const void* c2_b2 = d_in[13];

    const int* src = ei;
    const int* dst = ei + NEDGES;

    // -------- workspace layout (liveness-overlaid) --------
    uint8_t* w = (uint8_t*)d_ws;
    int* rowptr = (int*)(w + 0);
    int* counts = (int*)(w + 204800);
    int* cursor = (int*)(w + 409600);
    bf16* wT1 = (bf16*)(w + 204800);
    bf16* wT2 = (bf16*)(w + 270336);
    bf16* wT3 = (bf16*)(w + 409600);
    int* ssrc = (int*)(w + 614400);   // 3.2MB
    float* bnbuf = (float*)(w + 3814400);
    float* sum1 = bnbuf, *sumsq1 = bnbuf + 256;
    float* sc1 = bnbuf + 1312, *off1 = bnbuf + 1568;
    float* sc2 = bnbuf + 1824, *off2 = bnbuf + 2224;
    int* flag_in = (int*)(bnbuf + 2624);
    int* blocksums = (int*)(bnbuf + 2640);
    ushort* dummyrow = (ushort*)(bnbuf + 2840);
    uint8_t* bufA = w + 3830784;   // 20MB: out1 -> ps1/pq1 -> h1 -> pg/G -> fscr
    uint8_t* bufB = w + 23830784;  // 25.6MB: M1 -> t1 -> out2
    bf16* out1 = (bf16*)bufA;
    bf16* h1 = (bf16*)bufA;
    float* fscr = (float*)bufA;            // 1.6MB, live after greduce
    float* pg = (float*)bufA;              // 16.6MB (h1 dead by then)
    float* Gm = (float*)(bufA + 17000000);
    bf16* M1 = (bf16*)bufB;
    bf16* t1 = (bf16*)bufB;
    bf16* out2 = (bf16*)bufB;
    float* ps1 = (float*)(bufA + 12800000);           // NBB*8 x 256 = 3.2MB
    float* pq1 = ps1 + (size_t)NBB * 8 * MID1;        // +3.2MB (ends 19.2MB)

    hipMemsetAsync(counts, 0, NNODES * sizeof(int), stream);
    hipMemsetAsync(bnbuf, 0, 1312 * sizeof(float), stream);

    // CSR build
    hist_kernel<<<(NEDGES + 255) / 256, 256, 0, stream>>>(dst, counts, c1_g, flag_in);
    scanA_kernel<<<SCAN_NB, 256, 0, stream>>>(counts, rowptr, blocksums);
    scanC_kernel<<<SCAN_NB, 256, 0, stream>>>(rowptr, cursor, blocksums);
    scatter_kernel<<<(NEDGES + 255) / 256, 256, 0, stream>>>(src, dst, cursor, ssrc);

    // weight transposes + M1 msg table + dummy row
    prep_kernel<<<(NNODES * DIN / 4 + 255) / 256, 256, 0, stream>>>(
        c1_w1, wT1, c1_w2, wT2, c2_w1, wT3, x, M1, dummyrow, flag_in);

    // ----- layer 1 -----
    agg1_kernel<<<NNODES / 8, 256, 0, stream>>>(x, M1, rowptr, ssrc, flag_in, out1);
    bgemm<0, 16, 128, 256><<<dim3(NBB, 1), 512, 0, stream>>>(
        out1, wT1, c1_b1, flag_in, nullptr, nullptr, nullptr,
        t1, MID1, ps1, pq1, nullptr, NNODES);
    stats_reduce<<<dim3((MID1 + 63) / 64, RSPLIT), 256, 0, stream>>>(ps1, pq1, sum1, sumsq1,
                                                                     NBB * 8, MID1);
    bn_finish<<<1, 256, 0, stream>>>(sum1, sumsq1, c1_g, c1_be, flag_in, sc1, off1, MID1);
    bgemm<1, 7, 256, 100><<<dim3(NBB, 2), 512, 0, stream>>>(
        t1, wT2, c1_b2, flag_in, sc1, off1, nullptr,
        h1, DHID, nullptr, nullptr, nullptr, NNODES);

    // ----- layer 2 -----
    agg2_kernel<<<NNODES / 4, 256, 0, stream>>>(h1, rowptr, ssrc, dummyrow, out2);
    gram_kernel<<<GK_SPLIT, 512, 0, stream>>>(out2, pg);
    greduce_kernel<<<(GCH * GCH + 255) / 256, 256, 0, stream>>>(pg, Gm);
    bn2_finish<<<MID2, 256, 0, stream>>>(Gm, wT3, c2_b1, c2_g, c2_be, flag_in, sc2, off2);
    bgemm<2, 7, 200, 100><<<dim3(NBB, 4), 512, 0, stream>>>(
        out2, wT3, c2_b1, flag_in, sc2, off2, c2_w2,
        nullptr, 0, nullptr, nullptr, fscr, NNODES);
    final_combine<<<(NNODES + 255) / 256, 256, 0, stream>>>(fscr, c2_b2, flag_in,
                                                            d_out, NNODES);
}

// Round 5
// 374.407 us; speedup vs baseline: 1.4246x; 1.1438x over previous
//
#include <hip/hip_runtime.h>
#include <hip/hip_bf16.h>
#include <stdint.h>

#define NNODES 50000
#define NEDGES 800000
#define DIN 128
#define DHID 200
#define MID1 256
#define MID2 400
#define SCAN_NB ((NNODES + 255) / 256)  // 196
#define NBB ((NNODES + 127) / 128)      // 391 row-blocks (128 rows, 8 waves)
#define RSPLIT 12
#define LOG2E 1.4426950408889634f
#define LN2 0.6931471805599453f
// Gram (layer-2 BN stats): G = [out2 | 1]^T [out2 | 1], 208x208 padded
#define GK_SPLIT 96
#define GCH 208
#define GNP 40
// binned CSR build: buckets of 512 nodes by dst>>9
#define NBUCK 98
#define BCAP 16384
#define EPB 4096  // edges per bin block

typedef __hip_bfloat16 bf16;
typedef __attribute__((ext_vector_type(8))) short short8;
typedef __attribute__((ext_vector_type(4))) float floatx4;
typedef unsigned short ushort;

__device__ __forceinline__ float b2f(bf16 v) { return __bfloat162float(v); }
__device__ __forceinline__ bf16 f2b(float v) { return __float2bfloat16(v); }
__device__ __forceinline__ float bits2f(ushort b) {
    unsigned u = ((unsigned)b) << 16;
    return __uint_as_float(u);
}
__device__ __forceinline__ ushort f2bits(float f) {
    bf16 h = __float2bfloat16(f);
    return *(ushort*)&h;
}
__device__ __forceinline__ float ldin(const void* p, size_t i, int f32) {
    return f32 ? ((const float*)p)[i] : __bfloat162float(((const bf16*)p)[i]);
}
__device__ __forceinline__ void ldin4(const void* p, size_t i, int f32, float* v) {
    if (f32) {
        float4 f = *(const float4*)((const float*)p + i);
        v[0] = f.x; v[1] = f.y; v[2] = f.z; v[3] = f.w;
    } else {
        ushort4 u = *(const ushort4*)((const bf16*)p + i);
        v[0] = bits2f(u.x); v[1] = bits2f(u.y); v[2] = bits2f(u.z); v[3] = bits2f(u.w);
    }
}
__device__ __forceinline__ float fexp2(float x) {
#if __has_builtin(__builtin_amdgcn_exp2f)
    return __builtin_amdgcn_exp2f(x);
#else
    return exp2f(x);
#endif
}
__device__ __forceinline__ floatx4 mfma16(short8 a, short8 b, floatx4 c) {
    return __builtin_amdgcn_mfma_f32_16x16x32_bf16(a, b, c, 0, 0, 0);
}
// exp2-domain softmax accumulate over 4 packed channels
__device__ __forceinline__ void acc4(ushort4 u, float* s, float* p) {
    ushort uu[4];
    *(ushort4*)uu = u;
#pragma unroll
    for (int c = 0; c < 4; c++) {
        float v = bits2f(uu[c]);
        float ee = fexp2(v);
        s[c] += ee;
        p[c] = fmaf(v, ee, p[c]);
    }
}

// ---------------- binned CSR build ----------------
// Pass A: bin edges by dst>>9 into 98 bucket arrays (packed (dst<<16)|src).
// Per-block LDS count -> one global-atomic range reservation per bucket ->
// contiguous run writes. Kills the 16x write-amplification of random scatter.
__global__ __launch_bounds__(256) void bin_kernel(const int* __restrict__ src,
                                                  const int* __restrict__ dst,
                                                  const void* __restrict__ g,
                                                  int* __restrict__ flag,
                                                  unsigned* __restrict__ bbuf,
                                                  int* __restrict__ gcur) {
    __shared__ int cnt[NBUCK], cur[NBUCK];
    int tid = threadIdx.x;
    if (blockIdx.x == 0 && tid == 0)
        *flag = (((const unsigned*)g)[0] == 0x3F800000u) ? 1 : 0;
    if (tid < NBUCK) cnt[tid] = 0;
    __syncthreads();
    int e0 = blockIdx.x * EPB;
    unsigned pk[16];
    int bk[16];
#pragma unroll
    for (int i = 0; i < 16; i++) {
        int e = e0 + i * 256 + tid;
        if (e < NEDGES) {
            int d = dst[e], s = src[e];
            pk[i] = ((unsigned)d << 16) | (unsigned)s;
            bk[i] = d >> 9;
            atomicAdd(&cnt[bk[i]], 1);
        } else {
            bk[i] = -1;
        }
    }
    __syncthreads();
    if (tid < NBUCK) cur[tid] = atomicAdd(&gcur[tid], cnt[tid]);
    __syncthreads();
#pragma unroll
    for (int i = 0; i < 16; i++) {
        if (bk[i] >= 0) {
            int off = atomicAdd(&cur[bk[i]], 1);
            bbuf[(size_t)bk[i] * BCAP + off] = pk[i];
        }
    }
}

// Pass B1: per-bucket node histogram in LDS (replaces 800K global atomics),
// counts written coalesced (all nodes covered -> no memset needed).
__global__ __launch_bounds__(256) void histb_kernel(const unsigned* __restrict__ bbuf,
                                                    const int* __restrict__ gcur,
                                                    int* __restrict__ counts) {
    __shared__ int hc[512];
    int b = blockIdx.x, tid = threadIdx.x;
    int base = b << 9;
    int nn = min(512, NNODES - base);
    for (int i = tid; i < 512; i += 256) hc[i] = 0;
    __syncthreads();
    int cnt = gcur[b];
    const unsigned* eb = bbuf + (size_t)b * BCAP;
    for (int i = tid; i < cnt; i += 256) atomicAdd(&hc[(eb[i] >> 16) - base], 1);
    __syncthreads();
    for (int i = tid; i < nn; i += 256) counts[base + i] = hc[i];
}

// Pass B2: per-bucket scatter with LDS cursors; ssrc writes confined to a
// ~32KB window (single-XCD L2 resident -> each line evicted once).
__global__ __launch_bounds__(512) void scatterb_kernel(const unsigned* __restrict__ bbuf,
                                                       const int* __restrict__ gcur,
                                                       const int* __restrict__ rowptr,
                                                       int* __restrict__ ssrc) {
    __shared__ int lc[512];
    int b = blockIdx.x, tid = threadIdx.x;
    int base = b << 9;
    int nn = min(512, NNODES - base);
    lc[tid] = (tid < nn) ? rowptr[base + tid] : 0;
    __syncthreads();
    int cnt = gcur[b];
    const unsigned* eb = bbuf + (size_t)b * BCAP;
    for (int i = tid; i < cnt; i += 512) {
        unsigned p = eb[i];
        int node = (int)(p >> 16) - base;
        int idx = atomicAdd(&lc[node], 1);
        ssrc[idx] = (int)(p & 0xFFFFu);
    }
}

__global__ __launch_bounds__(256) void scanA_kernel(const int* __restrict__ counts,
                                                    int* __restrict__ rowptr,
                                                    int* __restrict__ blocksums) {
    __shared__ int sh[256];
    int t = threadIdx.x, b = blockIdx.x;
    int i = b * 256 + t;
    int v = (i < NNODES) ? counts[i] : 0;
    sh[t] = v;
    __syncthreads();
#pragma unroll
    for (int off = 1; off < 256; off <<= 1) {
        int o = (t >= off) ? sh[t - off] : 0;
        __syncthreads();
        sh[t] += o;
        __syncthreads();
    }
    if (i < NNODES) rowptr[i] = sh[t] - v;
    if (t == 255) blocksums[b] = sh[255];
}

__global__ __launch_bounds__(256) void scanC_kernel(int* __restrict__ rowptr,
                                                    const int* __restrict__ blocksums) {
    __shared__ int sh[256];
    int t = threadIdx.x, b = blockIdx.x;
    sh[t] = (t < SCAN_NB) ? blocksums[t] : 0;
    __syncthreads();
#pragma unroll
    for (int off = 1; off < 256; off <<= 1) {
        int o = (t >= off) ? sh[t - off] : 0;
        __syncthreads();
        sh[t] += o;
        __syncthreads();
    }
    int boff = (b > 0) ? sh[b - 1] : 0;
    int i = b * 256 + t;
    if (i < NNODES) rowptr[i] += boff;
    if (i == 0) rowptr[NNODES] = NEDGES;
}

// ---------------- prep: 3 weight transposes + M1 exp2-domain msg table ----------------
#define TW (DIN * MID1 + MID1 * DHID + DHID * MID2)  // 163968
__global__ __launch_bounds__(256) void prep_kernel(const void* __restrict__ W1, bf16* __restrict__ Wt1,
                                                   const void* __restrict__ W2, bf16* __restrict__ Wt2,
                                                   const void* __restrict__ W3, bf16* __restrict__ Wt3,
                                                   const void* __restrict__ X, bf16* __restrict__ M1,
                                                   ushort* __restrict__ dummy,
                                                   const int* __restrict__ flag) {
    const int S1 = DIN * MID1, S2 = MID1 * DHID;
    int f32 = *flag;
    int idx = blockIdx.x * 256 + threadIdx.x;
    if (idx < TW) {
        const void* W;
        bf16* Wt;
        int K, N, li;
        if (idx < S1) { W = W1; Wt = Wt1; K = DIN; N = MID1; li = idx; }
        else if (idx < S1 + S2) { W = W2; Wt = Wt2; K = MID1; N = DHID; li = idx - S1; }
        else { W = W3; Wt = Wt3; K = DHID; N = MID2; li = idx - S1 - S2; }
        int k = li / N, n = li - k * N;
        Wt[(size_t)n * K + k] = f2b(ldin(W, li, f32));
    }
    if (idx < DHID) dummy[idx] = 0xC300;  // bf16(-128): exp2 -> 0, softmax no-op
    int i = idx * 4;
    if (i < NNODES * DIN) {
        float v[4];
        ldin4(X, i, f32, v);
        ushort4 o;
        o.x = f2bits((fmaxf(v[0], 0.f) + 1e-7f) * LOG2E);
        o.y = f2bits((fmaxf(v[1], 0.f) + 1e-7f) * LOG2E);
        o.z = f2bits((fmaxf(v[2], 0.f) + 1e-7f) * LOG2E);
        o.w = f2bits((fmaxf(v[3], 0.f) + 1e-7f) * LOG2E);
        *(ushort4*)(M1 + i) = o;
    }
}

// ---------------- aggregation ----------
// DIN=128: 2 nodes per wave (half-wave = 32 lanes x 4 ch)
__global__ __launch_bounds__(256) void agg1_kernel(const void* __restrict__ X,
                                                   const bf16* __restrict__ M1,
                                                   const int* __restrict__ rowptr,
                                                   const int* __restrict__ ssrc,
                                                   const int* __restrict__ flag,
                                                   bf16* __restrict__ out) {
    int f32 = *flag;
    int hl = threadIdx.x & 31;
    int n = blockIdx.x * 8 + (threadIdx.x >> 5);
    int r0 = rowptr[n];
    int deg = rowptr[n + 1] - r0;
    const char* M1b = (const char*)M1;
    int boff = hl << 3;
    float s[4] = {0.f, 0.f, 0.f, 0.f}, p[4] = {0.f, 0.f, 0.f, 0.f};
    for (int base = 0; base < deg; base += 32) {
        int cnt = min(32, deg - base);
        int eo = ((base + hl < deg) ? ssrc[r0 + base + hl] : 0) << 8;
        int i = 0;
        for (; i + 7 < cnt; i += 8) {
            ushort4 u[8];
#pragma unroll
            for (int k = 0; k < 8; k++) {
                int o = __shfl(eo, i + k, 32) + boff;
                u[k] = *(const ushort4*)(M1b + o);
            }
#pragma unroll
            for (int k = 0; k < 8; k++) acc4(u[k], s, p);
        }
        for (; i < cnt; i++) {
            int o = __shfl(eo, i, 32) + boff;
            acc4(*(const ushort4*)(M1b + o), s, p);
        }
    }
    float xc[4];
    ldin4(X, (size_t)n * DIN + 4 * hl, f32, xc);
    ushort4 o;
    o.x = f2bits(fmaf(LN2, p[0] / (s[0] + 1e-16f), xc[0]));
    o.y = f2bits(fmaf(LN2, p[1] / (s[1] + 1e-16f), xc[1]));
    o.z = f2bits(fmaf(LN2, p[2] / (s[2] + 1e-16f), xc[2]));
    o.w = f2bits(fmaf(LN2, p[3] / (s[3] + 1e-16f), xc[3]));
    *(ushort4*)(out + (size_t)n * DIN + 4 * hl) = o;
}

// DHID=200: 1 node per wave (lanes 0..49 x 4 ch); M2 holds (h+eps)*log2e.
// Wave-uniform edge indices -> scalar loads; remainder via dummy(-128) row.
__global__ __launch_bounds__(256) void agg2_kernel(const bf16* __restrict__ M2,
                                                   const int* __restrict__ rowptr,
                                                   const int* __restrict__ ssrc,
                                                   const ushort* __restrict__ dummy,
                                                   bf16* __restrict__ out) {
    int lane = threadIdx.x & 63;
    int n = blockIdx.x * 4 + (threadIdx.x >> 6);
    int r0 = __builtin_amdgcn_readfirstlane(rowptr[n]);
    int deg = __builtin_amdgcn_readfirstlane(rowptr[n + 1]) - r0;
    bool act = lane < 50;
    int boff = (act ? lane : 49) << 3;
    const char* M2b = (const char*)M2;
    const char* dp = (const char*)dummy;
    float s[4] = {0.f, 0.f, 0.f, 0.f}, p[4] = {0.f, 0.f, 0.f, 0.f};
    int nfull = deg >> 3;
    for (int b = 0; b < nfull; b++) {
        const int* ep = ssrc + r0 + (b << 3);  // uniform -> s_load
        ushort4 u[8];
#pragma unroll
        for (int k = 0; k < 8; k++)
            u[k] = *(const ushort4*)(M2b + (size_t)((unsigned)ep[k] * 400u) + boff);
#pragma unroll
        for (int k = 0; k < 8; k++) acc4(u[k], s, p);
    }
    int rem = deg & 7;
    if (rem) {
        const int* ep = ssrc + r0 + (nfull << 3);
        ushort4 u[8];
#pragma unroll
        for (int k = 0; k < 8; k++) {
            const char* rp = (k < rem) ? (M2b + (size_t)((unsigned)ep[k] * 400u)) : dp;
            u[k] = *(const ushort4*)(rp + boff);
        }
#pragma unroll
        for (int k = 0; k < 8; k++) acc4(u[k], s, p);
    }
    if (act) {
        ushort4 u = *(const ushort4*)(M2b + (size_t)n * 400 + boff);
        float vn[4] = {bits2f(u.x), bits2f(u.y), bits2f(u.z), bits2f(u.w)};
        ushort4 o;
        o.x = f2bits(LN2 * (p[0] / (s[0] + 1e-16f) + vn[0]) - 1e-7f);
        o.y = f2bits(LN2 * (p[1] / (s[1] + 1e-16f) + vn[1]) - 1e-7f);
        o.z = f2bits(LN2 * (p[2] / (s[2] + 1e-16f) + vn[2]) - 1e-7f);
        o.w = f2bits(LN2 * (p[3] / (s[3] + 1e-16f) + vn[3]) - 1e-7f);
        *(ushort4*)(out + (size_t)n * DHID + 4 * lane) = o;
    }
}

// ---------------- B-stationary barrier-free GEMM ----------------
// MODE 0: G1  out=t1 raw + per-wave psum/psq         (NCOL=256, KK=128)
// MODE 1: G2  A-transform relu(a*sc+off); msg-store  (NCOL=100 x2, KK=256)
// MODE 2: FF  BN2+relu+w2 row-reduce -> fscr         (NCOL=100 x4, KK=200)
template <int MODE, int NT, int KK, int NCOL>
__global__ __launch_bounds__(512, 4) void bgemm(const bf16* __restrict__ A,
                                                const bf16* __restrict__ Bt,
                                                const void* __restrict__ bias,
                                                const int* __restrict__ flag,
                                                const float* __restrict__ sc,
                                                const float* __restrict__ offs,
                                                const void* __restrict__ w2,
                                                bf16* __restrict__ Out, int ostride,
                                                float* __restrict__ psum,
                                                float* __restrict__ psq,
                                                float* __restrict__ fscr, int M) {
    constexpr int KP = (KK + 31) & ~31;
    constexpr int KS = KP / 32;
    constexpr int KV8 = KP / 8;
    __shared__ short Bs[NT * 16][KP + 8];
    int f32 = *flag;
    int tid = threadIdx.x;
    int cb = blockIdx.y * NCOL;

    // stage whole B tile (zero-fill pads)
    for (int idx = tid; idx < NT * 16 * KV8; idx += 512) {
        int col = idx / KV8, kq = (idx - col * KV8) * 8;
        uint4 v = {0, 0, 0, 0};
        if (col < NCOL && kq < KK) v = *(const uint4*)(Bt + (size_t)(cb + col) * KK + kq);
        *(uint4*)&Bs[col][kq] = v;
    }
    __syncthreads();

    int w = tid >> 6, L = tid & 63;
    int lm = L & 15, q = L >> 4;
    int rw = blockIdx.x * 128 + w * 16;
    int ar = rw + lm;
    bool rok = ar < M;

    // prefetch ALL A fragments for this wave's 16 rows
    uint4 af[KS];
#pragma unroll
    for (int s = 0; s < KS; s++) {
        int k = s * 32 + q * 8;
        af[s] = (uint4){0, 0, 0, 0};
        if (rok && k + 8 <= KK) af[s] = *(const uint4*)(A + (size_t)ar * KK + k);
    }

    floatx4 acc[NT];
#pragma unroll
    for (int t = 0; t < NT; t++) acc[t] = (floatx4){0.f, 0.f, 0.f, 0.f};

#pragma unroll
    for (int s = 0; s < KS; s++) {
        short8 as;
        if (MODE == 1) {
            int ch = s * 32 + q * 8;
            float4 sA = *(const float4*)(sc + ch), sB = *(const float4*)(sc + ch + 4);
            float4 oA = *(const float4*)(offs + ch), oB = *(const float4*)(offs + ch + 4);
            float scv[8] = {sA.x, sA.y, sA.z, sA.w, sB.x, sB.y, sB.z, sB.w};
            float ofv[8] = {oA.x, oA.y, oA.z, oA.w, oB.x, oB.y, oB.z, oB.w};
            ushort us[8];
            *(uint4*)us = af[s];
#pragma unroll
            for (int j = 0; j < 8; j++)
                us[j] = f2bits(fmaxf(fmaf(bits2f(us[j]), scv[j], ofv[j]), 0.f));
            as = *(short8*)us;
        } else {
            as = *(short8*)&af[s];
        }
#pragma unroll
        for (int t = 0; t < NT; t++) {
            short8 bf = *(const short8*)&Bs[t * 16 + lm][s * 32 + q * 8];
            acc[t] = mfma16(as, bf, acc[t]);
        }
    }

    if (MODE == 0) {
#pragma unroll
        for (int t = 0; t < NT; t++) {
            int col = t * 16 + lm;
            float bb = ldin(bias, col, f32);
            float cs = 0.f, cq = 0.f;
#pragma unroll
            for (int r = 0; r < 4; r++) {
                int gm = rw + q * 4 + r;
                if (gm < M) {
                    float v = acc[t][r] + bb;
                    Out[(size_t)gm * ostride + col] = f2b(v);
                    cs += v;
                    cq += v * v;
                }
            }
            cs += __shfl_xor(cs, 16, 64); cq += __shfl_xor(cq, 16, 64);
            cs += __shfl_xor(cs, 32, 64); cq += __shfl_xor(cq, 32, 64);
            if (q == 0) {
                psum[(size_t)(blockIdx.x * 8 + w) * (NT * 16) + col] = cs;
                psq[(size_t)(blockIdx.x * 8 + w) * (NT * 16) + col] = cq;
            }
        }
    }
    if (MODE == 1) {
#pragma unroll
        for (int t = 0; t < NT; t++) {
            int col = t * 16 + lm;
            if (col < NCOL) {
                int gg = cb + col;
                float bb = ldin(bias, gg, f32);
#pragma unroll
                for (int r = 0; r < 4; r++) {
                    int gm = rw + q * 4 + r;
                    if (gm < M) {
                        float v = acc[t][r] + bb;
                        Out[(size_t)gm * ostride + gg] = f2b((fmaxf(v, 0.f) + 1e-7f) * LOG2E);
                    }
                }
            }
        }
    }
    if (MODE == 2) {
        float s0[4] = {0.f, 0.f, 0.f, 0.f}, s1[4] = {0.f, 0.f, 0.f, 0.f};
#pragma unroll
        for (int t = 0; t < NT; t++) {
            int col = t * 16 + lm;
            if (col < NCOL) {
                int gg = cb + col;
                float bb = ldin(bias, gg, f32);
                float scv = sc[gg], ofv = offs[gg];
                float w20 = ldin(w2, 2 * gg, f32), w21 = ldin(w2, 2 * gg + 1, f32);
#pragma unroll
                for (int r = 0; r < 4; r++) {
                    float vn = fmaxf((acc[t][r] + bb) * scv + ofv, 0.f);
                    s0[r] = fmaf(vn, w20, s0[r]);
                    s1[r] = fmaf(vn, w21, s1[r]);
                }
            }
        }
#pragma unroll
        for (int d = 1; d < 16; d <<= 1) {
#pragma unroll
            for (int r = 0; r < 4; r++) {
                s0[r] += __shfl_xor(s0[r], d, 64);
                s1[r] += __shfl_xor(s1[r], d, 64);
            }
        }
        if (lm == 0) {
#pragma unroll
            for (int r = 0; r < 4; r++) {
                int gm = rw + q * 4 + r;
                if (gm < M) {
                    fscr[(size_t)gm * 8 + blockIdx.y * 2 + 0] = s0[r];
                    fscr[(size_t)gm * 8 + blockIdx.y * 2 + 1] = s1[r];
                }
            }
        }
    }
}

// two-stage stats reduction (layer 1)
__global__ __launch_bounds__(256) void stats_reduce(const float* __restrict__ psum,
                                                    const float* __restrict__ psq,
                                                    float* __restrict__ bnsum,
                                                    float* __restrict__ bnsumsq,
                                                    int NB, int NC) {
    __shared__ float shs[4][64], shq[4][64];
    int cc = threadIdx.x & 63;
    int c = blockIdx.x * 64 + cc;
    int ro = threadIdx.x >> 6;
    int chunk = (NB + RSPLIT - 1) / RSPLIT;
    int b0 = blockIdx.y * chunk;
    int b1 = min(b0 + chunk, NB);
    float s = 0.f, sq = 0.f;
    if (c < NC) {
        for (int b = b0 + ro; b < b1; b += 4) {
            s += psum[(size_t)b * NC + c];
            sq += psq[(size_t)b * NC + c];
        }
    }
    shs[ro][cc] = s;
    shq[ro][cc] = sq;
    __syncthreads();
    if (threadIdx.x < 64) {
        int gc = blockIdx.x * 64 + threadIdx.x;
        if (gc < NC) {
            int t = threadIdx.x;
            float ts = shs[0][t] + shs[1][t] + shs[2][t] + shs[3][t];
            float tq = shq[0][t] + shq[1][t] + shq[2][t] + shq[3][t];
            atomicAdd(&bnsum[gc], ts);
            atomicAdd(&bnsumsq[gc], tq);
        }
    }
}

// fold BN stats (layer 1): h_norm = h*sc + off
__global__ void bn_finish(const float* __restrict__ sum, const float* __restrict__ sumsq,
                          const void* __restrict__ g, const void* __restrict__ be,
                          const int* __restrict__ flag,
                          float* __restrict__ sc, float* __restrict__ off, int C) {
    int f32 = *flag;
    int c = blockIdx.x * blockDim.x + threadIdx.x;
    if (c < C) {
        float mu = sum[c] / (float)NNODES;
        float var = fmaxf(sumsq[c] / (float)NNODES - mu * mu, 0.f);
        float rstd = rsqrtf(var + 1e-5f);
        float s = rstd * ldin(g, c, f32);
        sc[c] = s;
        off[c] = ldin(be, c, f32) - mu * s;
    }
}

// ---------------- Gram kernel (layer-2 BN stats) ----------------
__global__ __launch_bounds__(512) void gram_kernel(const bf16* __restrict__ X,
                                                   float* __restrict__ pg) {
    __shared__ short T[GCH][GNP];
    int tid = threadIdx.x;
    int w = tid >> 6, L = tid & 63;
    int lm = L & 15, q = L >> 4;
    floatx4 acc[2][13];
#pragma unroll
    for (int c = 0; c < 2; c++)
#pragma unroll
        for (int t = 0; t < 13; t++) acc[c][t] = (floatx4){0.f, 0.f, 0.f, 0.f};

    const int chunks = (NNODES + 32 * GK_SPLIT - 1) / (32 * GK_SPLIT);  // 17
    int base0 = blockIdx.x * chunks * 32;
    for (int ch = 0; ch < chunks; ch++) {
        int nb = base0 + ch * 32;
#pragma unroll
        for (int p = 0; p < 4; p++) {
            int idx = tid + p * 512;
            if (idx < 1600) {
                int nl = idx & 31, cq = idx >> 5;
                int gn = nb + nl;
                ushort4 u = {0, 0, 0, 0};
                if (gn < NNODES) u = *(const ushort4*)(X + (size_t)gn * DHID + cq * 4);
                T[cq * 4 + 0][nl] = (short)u.x;
                T[cq * 4 + 1][nl] = (short)u.y;
                T[cq * 4 + 2][nl] = (short)u.z;
                T[cq * 4 + 3][nl] = (short)u.w;
            }
        }
        if (tid < 256) {
            int nl = tid & 31, c = 200 + (tid >> 5);
            int gn = nb + nl;
            T[c][nl] = (c == 200 && gn < NNODES) ? (short)0x3F80 : (short)0;
        }
        __syncthreads();
        short8 af[13];
#pragma unroll
        for (int t = 0; t < 13; t++) af[t] = *(const short8*)&T[t * 16 + lm][q * 8];
#pragma unroll
        for (int c = 0; c < 2; c++) {
            int cj = w + c * 8;
            if (cj < 13) {
                short8 bf = *(const short8*)&T[cj * 16 + lm][q * 8];
#pragma unroll
                for (int t = 0; t < 13; t++) acc[c][t] = mfma16(af[t], bf, acc[c][t]);
            }
        }
        __syncthreads();
    }
    float* pgb = pg + (size_t)blockIdx.x * (GCH * GCH);
#pragma unroll
    for (int c = 0; c < 2; c++) {
        int cj = w + c * 8;
        if (cj < 13) {
#pragma unroll
            for (int t = 0; t < 13; t++)
#pragma unroll
                for (int r = 0; r < 4; r++)
                    pgb[(size_t)(t * 16 + q * 4 + r) * GCH + cj * 16 + lm] = acc[c][t][r];
        }
    }
}

__global__ void greduce_kernel(const float* __restrict__ pg, float* __restrict__ G) {
    int e = blockIdx.x * 256 + threadIdx.x;
    if (e < GCH * GCH) {
        float s = 0.f;
        for (int b = 0; b < GK_SPLIT; b++) s += pg[(size_t)b * (GCH * GCH) + e];
        G[e] = s;
    }
}

// BN2 stats from Gram
__global__ __launch_bounds__(256) void bn2_finish(const float* __restrict__ G,
                                                  const bf16* __restrict__ Wt3,
                                                  const void* __restrict__ b1,
                                                  const void* __restrict__ g,
                                                  const void* __restrict__ be,
                                                  const int* __restrict__ flag,
                                                  float* __restrict__ sc,
                                                  float* __restrict__ off) {
    __shared__ float wl[200];
    __shared__ float red[256];
    __shared__ float dsh;
    int f32 = *flag;
    int c = blockIdx.x;
    int t = threadIdx.x;
    if (t < 200) wl[t] = b2f(Wt3[(size_t)c * DHID + t]);
    __syncthreads();
    float di = 0.f;
    if (t <= 200) {
        const float* Gr = G + (size_t)t * GCH;
        for (int j = 0; j < 200; j++) di = fmaf(Gr[j], wl[j], di);
    }
    red[t] = (t < 200) ? wl[t] * di : 0.f;
    if (t == 200) dsh = di;
    __syncthreads();
    for (int o = 128; o > 0; o >>= 1) {
        if (t < o) red[t] += red[t + o];
        __syncthreads();
    }
    if (t == 0) {
        float d = dsh;
        float bc = ldin(b1, c, f32);
        float mu = d / (float)NNODES + bc;
        float eh2 = (red[0] + 2.f * bc * d) / (float)NNODES + bc * bc;
        float var = fmaxf(eh2 - mu * mu, 0.f);
        float rstd = rsqrtf(var + 1e-5f);
        float s = rstd * ldin(g, c, f32);
        sc[c] = s;
        off[c] = ldin(be, c, f32) - mu * s;
    }
}

// combine the four col-quarter partials: out = relu(sum + b2)
__global__ void final_combine(const float* __restrict__ fscr, const void* __restrict__ b2,
                              const int* __restrict__ flag, void* __restrict__ outp, int M) {
    int f32 = *flag;
    int n = blockIdx.x * 256 + threadIdx.x;
    if (n < M) {
        const float* f = fscr + (size_t)n * 8;
        float v0 = fmaxf(f[0] + f[2] + f[4] + f[6] + ldin(b2, 0, f32), 0.f);
        float v1 = fmaxf(f[1] + f[3] + f[5] + f[7] + ldin(b2, 1, f32), 0.f);
        if (f32) {
            ((float*)outp)[2 * n] = v0;
            ((float*)outp)[2 * n + 1] = v1;
        } else {
            ((bf16*)outp)[2 * n] = f2b(v0);
            ((bf16*)outp)[2 * n + 1] = f2b(v1);
        }
    }
}

extern "C" void kernel_launch(void* const* d_in, const int* in_sizes, int n_in,
                              void* d_out, int out_size, void* d_ws, size_t ws_size,
                              hipStream_t stream) {
    const void* x = d_in[0];
    const int* ei = (const int*)d_in[1];
    const void* c1_w1 = d_in[2];
    const void* c1_b1 = d_in[3];
    const void* c1_g = d_in[4];
    const void* c1_be = d_in[5];
    const void* c1_w2 = d_in[6];
    const void* c1_b2 = d_in[7];
    const void* c2_w1 = d_in[8];
    const void* c2_b1 = d_in[9];
    const void* c2_g = d_in[10];
    const void* c2_be = d_in[11];
    const void* c2_w2 = d_in[12];
    const void* c2_b2 = d_in[13];

    const int* src = ei;
    const int* dst = ei + NEDGES;

    // -------- workspace layout (liveness-overlaid) --------
    uint8_t* w = (uint8_t*)d_ws;
    int* rowptr = (int*)(w + 0);
    int* counts = (int*)(w + 204800);
    bf16* wT1 = (bf16*)(w + 204800);   // overlays counts after scanA consumed it? NO:
    // counts consumed by scanA; wT1 written by prep AFTER scanA -> overlay safe.
    bf16* wT2 = (bf16*)(w + 270336);
    bf16* wT3 = (bf16*)(w + 409600);
    int* ssrc = (int*)(w + 614400);    // 3.2MB
    float* bnbuf = (float*)(w + 3814400);
    float* sum1 = bnbuf, *sumsq1 = bnbuf + 256;
    int* gcur = (int*)(bnbuf + 512);   // 98 ints, covered by the bnbuf memset
    float* sc1 = bnbuf + 1312, *off1 = bnbuf + 1568;
    float* sc2 = bnbuf + 1824, *off2 = bnbuf + 2224;
    int* flag_in = (int*)(bnbuf + 2624);
    int* blocksums = (int*)(bnbuf + 2640);
    ushort* dummyrow = (ushort*)(bnbuf + 2840);
    uint8_t* bufA = w + 3830784;   // 20MB: bbuf -> out1 -> ps1/pq1 -> h1 -> pg/G -> fscr
    uint8_t* bufB = w + 23830784;  // 25.6MB: M1 -> t1 -> out2
    unsigned* bbuf = (unsigned*)bufA;      // 98*16384*4 = 6.42MB, dead before agg1
    bf16* out1 = (bf16*)bufA;
    bf16* h1 = (bf16*)bufA;
    float* fscr = (float*)bufA;            // 1.6MB, live after greduce
    float* pg = (float*)bufA;              // 16.6MB (h1 dead by then)
    float* Gm = (float*)(bufA + 17000000);
    bf16* M1 = (bf16*)bufB;
    bf16* t1 = (bf16*)bufB;
    bf16* out2 = (bf16*)bufB;
    float* ps1 = (float*)(bufA + 12800000);           // NBB*8 x 256 = 3.2MB
    float* pq1 = ps1 + (size_t)NBB * 8 * MID1;        // +3.2MB (ends 19.2MB)

    hipMemsetAsync(bnbuf, 0, 1312 * sizeof(float), stream);  // sum1/sumsq1 + gcur

    // binned CSR build (replaces hist + random scatter; counts memset not needed)
    bin_kernel<<<(NEDGES + EPB - 1) / EPB, 256, 0, stream>>>(src, dst, c1_g, flag_in,
                                                             bbuf, gcur);
    histb_kernel<<<NBUCK, 256, 0, stream>>>(bbuf, gcur, counts);
    scanA_kernel<<<SCAN_NB, 256, 0, stream>>>(counts, rowptr, blocksums);
    scanC_kernel<<<SCAN_NB, 256, 0, stream>>>(rowptr, blocksums);
    scatterb_kernel<<<NBUCK, 512, 0, stream>>>(bbuf, gcur, rowptr, ssrc);

    // weight transposes + M1 msg table + dummy row
    prep_kernel<<<(NNODES * DIN / 4 + 255) / 256, 256, 0, stream>>>(
        c1_w1, wT1, c1_w2, wT2, c2_w1, wT3, x, M1, dummyrow, flag_in);

    // ----- layer 1 -----
    agg1_kernel<<<NNODES / 8, 256, 0, stream>>>(x, M1, rowptr, ssrc, flag_in, out1);
    bgemm<0, 16, 128, 256><<<dim3(NBB, 1), 512, 0, stream>>>(
        out1, wT1, c1_b1, flag_in, nullptr, nullptr, nullptr,
        t1, MID1, ps1, pq1, nullptr, NNODES);
    stats_reduce<<<dim3((MID1 + 63) / 64, RSPLIT), 256, 0, stream>>>(ps1, pq1, sum1, sumsq1,
                                                                     NBB * 8, MID1);
    bn_finish<<<1, 256, 0, stream>>>(sum1, sumsq1, c1_g, c1_be, flag_in, sc1, off1, MID1);
    bgemm<1, 7, 256, 100><<<dim3(NBB, 2), 512, 0, stream>>>(
        t1, wT2, c1_b2, flag_in, sc1, off1, nullptr,
        h1, DHID, nullptr, nullptr, nullptr, NNODES);

    // ----- layer 2 -----
    agg2_kernel<<<NNODES / 4, 256, 0, stream>>>(h1, rowptr, ssrc, dummyrow, out2);
    gram_kernel<<<GK_SPLIT, 512, 0, stream>>>(out2, pg);
    greduce_kernel<<<(GCH * GCH + 255) / 256, 256, 0, stream>>>(pg, Gm);
    bn2_finish<<<MID2, 256, 0, stream>>>(Gm, wT3, c2_b1, c2_g, c2_be, flag_in, sc2, off2);
    bgemm<2, 7, 200, 100><<<dim3(NBB, 4), 512, 0, stream>>>(
        out2, wT3, c2_b1, flag_in, sc2, off2, c2_w2,
        nullptr, 0, nullptr, nullptr, fscr, NNODES);
    final_combine<<<(NNODES + 255) / 256, 256, 0, stream>>>(fscr, c2_b2, flag_in,
                                                            d_out, NNODES);
}